// Round 6
// baseline (274.057 us; speedup 1.0000x reference)
//
#include <hip/hip_runtime.h>
#include <math.h>

#define EPSF 1e-5f

typedef __attribute__((ext_vector_type(8))) __bf16 bf16x8;
typedef __attribute__((ext_vector_type(4))) float f32x4;

__device__ __forceinline__ unsigned short f2bf(float f) {
  unsigned int u = __float_as_uint(f);
  u += 0x7FFFu + ((u >> 16) & 1u);
  return (unsigned short)(u >> 16);
}

// ---- fused: LN1+dt (blocks 0..2047) | weight transpose fp32->bf16 (2048..4095)
__global__ __launch_bounds__(256) void k_pre(
    const float* __restrict__ x, const float* __restrict__ g, const float* __restrict__ bta,
    const float* __restrict__ w_dt, const float* __restrict__ b_dt,
    const float* __restrict__ log_A, float* __restrict__ xn, float* __restrict__ log_a,
    const float* __restrict__ W1, unsigned short* __restrict__ W1t,
    const float* __restrict__ W2, unsigned short* __restrict__ W2t) {
  __shared__ float smem[64 * 65];
  int tid = threadIdx.x;
  if (blockIdx.x < 2048) {
    int bs = blockIdx.x;
    int t = tid;
    float4 v = ((const float4*)(x + (size_t)bs * 1024))[t];
    float s = v.x + v.y + v.z + v.w;
    float ss = v.x * v.x + v.y * v.y + v.z * v.z + v.w * v.w;
    #pragma unroll
    for (int o = 1; o < 64; o <<= 1) { s += __shfl_xor(s, o); ss += __shfl_xor(ss, o); }
    float* red = smem;
    int w = t >> 6;
    if ((t & 63) == 0) { red[w] = s; red[4 + w] = ss; }
    __syncthreads();
    float S = red[0] + red[1] + red[2] + red[3];
    float SS = red[4] + red[5] + red[6] + red[7];
    float m = S * (1.0f / 1024.0f);
    float var = SS * (1.0f / 1024.0f) - m * m;
    float inv = rsqrtf(var + EPSF);
    float4 gv = ((const float4*)g)[t];
    float4 bv = ((const float4*)bta)[t];
    float4 o;
    o.x = (v.x - m) * inv * gv.x + bv.x;
    o.y = (v.y - m) * inv * gv.y + bv.y;
    o.z = (v.z - m) * inv * gv.z + bv.z;
    o.w = (v.w - m) * inv * gv.w + bv.w;
    ((float4*)(xn + (size_t)bs * 1024))[t] = o;
    float4 wv = ((const float4*)w_dt)[t & 7];
    float part = o.x * wv.x + o.y * wv.y + o.z * wv.z + o.w * wv.w;
    part += __shfl_xor(part, 1);
    part += __shfl_xor(part, 2);
    part += __shfl_xor(part, 4);
    if ((t & 7) == 0) {
      int r = t >> 3;
      float z = part + b_dt[0];
      float sp = (z > 20.0f) ? z : log1pf(expf(z));
      log_a[(size_t)bs * 32 + r] = sp * (-expf(log_A[r]));
    }
  } else {
    int bid = blockIdx.x - 2048;
    const float* src; unsigned short* dst; int R, C, r0, c0;
    if (bid < 1024) { src = W1; dst = W1t; R = 1024; C = 4096;
                      c0 = (bid & 63) * 64; r0 = (bid >> 6) * 64; }
    else { bid -= 1024; src = W2; dst = W2t; R = 4096; C = 1024;
           c0 = (bid & 15) * 64; r0 = (bid >> 4) * 64; }
    #pragma unroll
    for (int q = 0; q < 4; ++q) {
      int lin = q * 256 + tid;
      int r = lin >> 4, cq = lin & 15;
      float4 v = *(const float4*)(src + (size_t)(r0 + r) * C + c0 + cq * 4);
      smem[r * 65 + cq * 4 + 0] = v.x; smem[r * 65 + cq * 4 + 1] = v.y;
      smem[r * 65 + cq * 4 + 2] = v.z; smem[r * 65 + cq * 4 + 3] = v.w;
    }
    __syncthreads();
    #pragma unroll
    for (int q = 0; q < 4; ++q) {
      int lin = q * 256 + tid;
      int c = lin >> 4, rq = lin & 15;
      ushort4 o;
      o.x = f2bf(smem[(rq * 4 + 0) * 65 + c]);
      o.y = f2bf(smem[(rq * 4 + 1) * 65 + c]);
      o.z = f2bf(smem[(rq * 4 + 2) * 65 + c]);
      o.w = f2bf(smem[(rq * 4 + 3) * 65 + c]);
      *(ushort4*)(dst + (size_t)(c0 + c) * R + r0 + rq * 4) = o;
    }
  }
}

// ---- chunked scan, float4 over c. grid (b,r,ch)=512; 256 thr = 32 sub x 8 cg
// PASS1 additionally writes out = ssm + bb2 (init for GEMM2's atomic accum).
template <int PASS>
__global__ __launch_bounds__(256) void k_scan_pass(
    const float* __restrict__ xn, const float* __restrict__ x,
    const float* __restrict__ loga, float4* __restrict__ E, float* __restrict__ P,
    float* __restrict__ ssm, const float* __restrict__ bb2, float* __restrict__ out) {
  int bx = blockIdx.x;
  int b = bx >> 8, r = (bx >> 3) & 31, ch = bx & 7;
  int tid = threadIdx.x, cg = tid & 7, sub = tid >> 3;
  __shared__ float dec[128];
  __shared__ float4 sE[32][8];
  __shared__ float sP[32];
  if (tid < 128)
    dec[tid] = expf(loga[(size_t)(b * 1024 + ch * 128 + tid) * 32 + r]);
  __syncthreads();
  int t0 = ch * 128 + sub * 4;
  size_t base = ((size_t)(b * 1024 + t0) * 1024 + r * 32 + cg * 4) >> 2;
  const float4* xn4 = (const float4*)xn;
  float4 xv[4];
  #pragma unroll
  for (int i = 0; i < 4; ++i) xv[i] = xn4[base + (size_t)i * 256];
  float4 S = {0.f, 0.f, 0.f, 0.f};
  float Pl = 1.0f;
  #pragma unroll
  for (int i = 0; i < 4; ++i) {
    float d = dec[sub * 4 + i];
    S.x = d * S.x + xv[i].x; S.y = d * S.y + xv[i].y;
    S.z = d * S.z + xv[i].z; S.w = d * S.w + xv[i].w;
    Pl *= d;
  }
  sE[sub][cg] = S;
  if (cg == 0) sP[sub] = Pl;
  __syncthreads();
  if (PASS == 0) {
    if (tid < 8) {
      float4 Et = {0.f, 0.f, 0.f, 0.f};
      float PP = 1.0f;
      #pragma unroll
      for (int h = 0; h < 32; ++h) {
        float p = sP[h]; float4 e = sE[h][tid];
        Et.x = p * Et.x + e.x; Et.y = p * Et.y + e.y;
        Et.z = p * Et.z + e.z; Et.w = p * Et.w + e.w;
        PP *= p;
      }
      E[((size_t)(b * 32 + r) * 8 + ch) * 8 + tid] = Et;
      if (tid == 0) P[(b * 32 + r) * 8 + ch] = PP;
    }
  } else {
    float4 Sin = {0.f, 0.f, 0.f, 0.f};
    const float4* Eb = E + (size_t)(b * 32 + r) * 64 + cg;
    const float* Pb = P + (size_t)(b * 32 + r) * 8;
    for (int h = 0; h < ch; ++h) {
      float p = Pb[h]; float4 e = Eb[h * 8];
      Sin.x = p * Sin.x + e.x; Sin.y = p * Sin.y + e.y;
      Sin.z = p * Sin.z + e.z; Sin.w = p * Sin.w + e.w;
    }
    for (int h = 0; h < sub; ++h) {
      float p = sP[h]; float4 e = sE[h][cg];
      Sin.x = p * Sin.x + e.x; Sin.y = p * Sin.y + e.y;
      Sin.z = p * Sin.z + e.z; Sin.w = p * Sin.w + e.w;
    }
    float4 bb = ((const float4*)bb2)[r * 8 + cg];
    const float4* x4 = (const float4*)x;
    float4* ssm4 = (float4*)ssm;
    float4* out4 = (float4*)out;
    #pragma unroll
    for (int i = 0; i < 4; ++i) {
      float d = dec[sub * 4 + i];
      Sin.x = d * Sin.x + xv[i].x; Sin.y = d * Sin.y + xv[i].y;
      Sin.z = d * Sin.z + xv[i].z; Sin.w = d * Sin.w + xv[i].w;
      float4 rx = x4[base + (size_t)i * 256];
      float4 o;
      o.x = Sin.x + rx.x; o.y = Sin.y + rx.y;
      o.z = Sin.z + rx.z; o.w = Sin.w + rx.w;
      ssm4[base + (size_t)i * 256] = o;
      float4 oi;
      oi.x = o.x + bb.x; oi.y = o.y + bb.y; oi.z = o.z + bb.z; oi.w = o.w + bb.w;
      out4[base + (size_t)i * 256] = oi;
    }
  }
}

// ---- LN2 -> fn bf16 ----
__global__ __launch_bounds__(256) void k_ln2(
    const float* __restrict__ ssm, const float* __restrict__ g, const float* __restrict__ bta,
    unsigned short* __restrict__ fn) {
  int bs = blockIdx.x;
  int t = threadIdx.x;
  float4 v = ((const float4*)(ssm + (size_t)bs * 1024))[t];
  float s = v.x + v.y + v.z + v.w;
  float ss = v.x * v.x + v.y * v.y + v.z * v.z + v.w * v.w;
  #pragma unroll
  for (int o = 1; o < 64; o <<= 1) { s += __shfl_xor(s, o); ss += __shfl_xor(ss, o); }
  __shared__ float red[8];
  int w = t >> 6;
  if ((t & 63) == 0) { red[w] = s; red[4 + w] = ss; }
  __syncthreads();
  float S = red[0] + red[1] + red[2] + red[3];
  float SS = red[4] + red[5] + red[6] + red[7];
  float m = S * (1.0f / 1024.0f);
  float var = SS * (1.0f / 1024.0f) - m * m;
  float inv = rsqrtf(var + EPSF);
  float4 gv = ((const float4*)g)[t];
  float4 bv = ((const float4*)bta)[t];
  ushort4 o;
  o.x = f2bf((v.x - m) * inv * gv.x + bv.x);
  o.y = f2bf((v.y - m) * inv * gv.y + bv.y);
  o.z = f2bf((v.z - m) * inv * gv.z + bv.z);
  o.w = f2bf((v.w - m) * inv * gv.w + bv.w);
  ((ushort4*)(fn + (size_t)bs * 1024))[t] = o;
}

// ---- DIRECT-LOAD bf16 MFMA GEMM: no LDS, no barriers. 128x128 block,
// 4 waves (2x2) of 64x64. MFMA fragments loaded straight from K-major
// global memory (dwordx4/lane); compiler software-pipelines via vmcnt.
// EPI 0: C(bf16) = gelu(acc + bias[n]).  EPI 1: atomicAdd fp32 into C.
template <int EPI, int K, int KS>
__global__ __launch_bounds__(256, 3) void k_gemm_d(
    const unsigned short* __restrict__ A, const unsigned short* __restrict__ Bt,
    const float* __restrict__ bias, void* __restrict__ C, int M, int N) {
  constexpr int KLEN = K / KS;
  int m0 = blockIdx.y * 128, n0 = blockIdx.x * 128;
  int kOff = (KS > 1) ? ((int)blockIdx.z * KLEN) : 0;
  int tid = threadIdx.x;
  int wave = tid >> 6, lane = tid & 63;
  int wr = wave >> 1, wc = wave & 1;
  int l15 = lane & 15, quad = lane >> 4;

  const unsigned short* pa = A + (size_t)(m0 + wr * 64 + l15) * K + kOff + quad * 8;
  const unsigned short* pb = Bt + (size_t)(n0 + wc * 64 + l15) * K + kOff + quad * 8;

  f32x4 zero = {0.0f, 0.0f, 0.0f, 0.0f};
  f32x4 acc[4][4];
  #pragma unroll
  for (int i = 0; i < 4; ++i)
    #pragma unroll
    for (int j = 0; j < 4; ++j) acc[i][j] = zero;

  #pragma unroll 2
  for (int k0 = 0; k0 < KLEN; k0 += 32) {
    bf16x8 af[4], bfr[4];
    #pragma unroll
    for (int i = 0; i < 4; ++i)
      af[i] = *(const bf16x8*)(pa + (size_t)i * 16 * K + k0);
    #pragma unroll
    for (int j = 0; j < 4; ++j)
      bfr[j] = *(const bf16x8*)(pb + (size_t)j * 16 * K + k0);
    #pragma unroll
    for (int i = 0; i < 4; ++i)
      #pragma unroll
      for (int j = 0; j < 4; ++j)
        acc[i][j] = __builtin_amdgcn_mfma_f32_16x16x32_bf16(af[i], bfr[j], acc[i][j], 0, 0, 0);
  }

  if (EPI == 0) {
    unsigned short* Cb = (unsigned short*)C;
    #pragma unroll
    for (int i = 0; i < 4; ++i)
      #pragma unroll
      for (int j = 0; j < 4; ++j) {
        int col = n0 + wc * 64 + j * 16 + l15;
        float bval = bias[col];
        #pragma unroll
        for (int v = 0; v < 4; ++v) {
          int row = m0 + wr * 64 + i * 16 + quad * 4 + v;
          float val = acc[i][j][v] + bval;
          val = 0.5f * val * (1.0f + erff(val * 0.70710678118654752f));
          Cb[(size_t)row * N + col] = f2bf(val);
        }
      }
  } else {
    float* O = (float*)C;
    #pragma unroll
    for (int i = 0; i < 4; ++i)
      #pragma unroll
      for (int j = 0; j < 4; ++j) {
        int col = n0 + wc * 64 + j * 16 + l15;
        #pragma unroll
        for (int v = 0; v < 4; ++v) {
          int row = m0 + wr * 64 + i * 16 + quad * 4 + v;
          atomicAdd(&O[(size_t)row * N + col], acc[i][j][v]);
        }
      }
  }
}

extern "C" void kernel_launch(void* const* d_in, const int* in_sizes, int n_in,
                              void* d_out, int out_size, void* d_ws, size_t ws_size,
                              hipStream_t stream) {
  const float* x     = (const float*)d_in[0];
  const float* log_A = (const float*)d_in[1];
  const float* w_dt  = (const float*)d_in[2];
  const float* b_dt  = (const float*)d_in[3];
  const float* g_ssm = (const float*)d_in[4];
  const float* b_ssm = (const float*)d_in[5];
  const float* g_ffn = (const float*)d_in[6];
  const float* b_ffn = (const float*)d_in[7];
  const float* W1    = (const float*)d_in[8];
  const float* bb1   = (const float*)d_in[9];
  const float* W2    = (const float*)d_in[10];
  const float* bb2   = (const float*)d_in[11];
  float* out = (float*)d_out;

  const size_t MB = 1u << 20;
  char* ws = (char*)d_ws;
  float* xn            = (float*)(ws);                       // 0-8
  unsigned short* W1t  = (unsigned short*)(ws + 8 * MB);     // 8-16
  float* loga          = (float*)(ws + 16 * MB);
  float4* Ebuf         = (float4*)(ws + 16 * MB + 262144);
  float* Pbuf          = (float*)(ws + 16 * MB + 393216);
  unsigned short* fn   = (unsigned short*)(ws + 17 * MB);    // 17-21
  unsigned short* W2t  = (unsigned short*)(ws + 21 * MB);    // 21-29
  float* ssm           = (float*)(ws + 29 * MB);             // 29-37
  unsigned short* hbf  = (unsigned short*)(ws + 37 * MB);    // 37-53

  k_pre<<<4096, 256, 0, stream>>>(x, g_ssm, b_ssm, w_dt, b_dt, log_A, xn, loga,
                                  W1, W1t, W2, W2t);
  k_scan_pass<0><<<512, 256, 0, stream>>>(xn, x, loga, Ebuf, Pbuf, ssm, bb2, out);
  k_scan_pass<1><<<512, 256, 0, stream>>>(xn, x, loga, Ebuf, Pbuf, ssm, bb2, out);
  k_ln2<<<2048, 256, 0, stream>>>(ssm, g_ffn, b_ffn, fn);
  // GEMM1: 128x128 tiles, grid 32x16 = 512 blocks, K=1024
  k_gemm_d<0, 1024, 1><<<dim3(32, 16, 1), 256, 0, stream>>>(
      fn, W1t, bb1, (void*)hbf, 2048, 4096);
  // GEMM2: 128x128 tiles, split-K=4 (kLen=1024), atomic accumulate into out
  k_gemm_d<1, 4096, 4><<<dim3(8, 16, 4), 256, 0, stream>>>(
      hbf, W2t, nullptr, (void*)out, 2048, 1024);
}

// Round 7
// 205.091 us; speedup vs baseline: 1.3363x; 1.3363x over previous
//
#include <hip/hip_runtime.h>
#include <math.h>

#define EPSF 1e-5f

typedef __attribute__((ext_vector_type(8))) __bf16 bf16x8;
typedef __attribute__((ext_vector_type(4))) float f32x4;

__device__ __forceinline__ unsigned short f2bf(float f) {
  unsigned int u = __float_as_uint(f);
  u += 0x7FFFu + ((u >> 16) & 1u);
  return (unsigned short)(u >> 16);
}

// Packed fragment-major layout for MFMA operands:
//   element (row, k) lives at  ((rowTile*NKG + kg)*512 + quad*128 + (row&15)*8 + (k&7))
//   where rowTile=row>>4, kg=k>>5, quad=(k>>3)&3.
// A wave's 16x32 fragment = one contiguous 1KB block (lane*16B), fully coalesced.

// ---- fused: LN1+dt (blocks 0..2047) | weight transpose+pack (2048..4095) ----
__global__ __launch_bounds__(256) void k_pre(
    const float* __restrict__ x, const float* __restrict__ g, const float* __restrict__ bta,
    const float* __restrict__ w_dt, const float* __restrict__ b_dt,
    const float* __restrict__ log_A, float* __restrict__ xn, float* __restrict__ log_a,
    const float* __restrict__ W1, unsigned short* __restrict__ W1t,
    const float* __restrict__ W2, unsigned short* __restrict__ W2t) {
  __shared__ float smem[64 * 65];
  int tid = threadIdx.x;
  if (blockIdx.x < 2048) {
    int bs = blockIdx.x;
    int t = tid;
    float4 v = ((const float4*)(x + (size_t)bs * 1024))[t];
    float s = v.x + v.y + v.z + v.w;
    float ss = v.x * v.x + v.y * v.y + v.z * v.z + v.w * v.w;
    #pragma unroll
    for (int o = 1; o < 64; o <<= 1) { s += __shfl_xor(s, o); ss += __shfl_xor(ss, o); }
    float* red = smem;
    int w = t >> 6;
    if ((t & 63) == 0) { red[w] = s; red[4 + w] = ss; }
    __syncthreads();
    float S = red[0] + red[1] + red[2] + red[3];
    float SS = red[4] + red[5] + red[6] + red[7];
    float m = S * (1.0f / 1024.0f);
    float var = SS * (1.0f / 1024.0f) - m * m;
    float inv = rsqrtf(var + EPSF);
    float4 gv = ((const float4*)g)[t];
    float4 bv = ((const float4*)bta)[t];
    float4 o;
    o.x = (v.x - m) * inv * gv.x + bv.x;
    o.y = (v.y - m) * inv * gv.y + bv.y;
    o.z = (v.z - m) * inv * gv.z + bv.z;
    o.w = (v.w - m) * inv * gv.w + bv.w;
    ((float4*)(xn + (size_t)bs * 1024))[t] = o;
    float4 wv = ((const float4*)w_dt)[t & 7];
    float part = o.x * wv.x + o.y * wv.y + o.z * wv.z + o.w * wv.w;
    part += __shfl_xor(part, 1);
    part += __shfl_xor(part, 2);
    part += __shfl_xor(part, 4);
    if ((t & 7) == 0) {
      int r = t >> 3;
      float z = part + b_dt[0];
      float sp = (z > 20.0f) ? z : log1pf(expf(z));
      log_a[(size_t)bs * 32 + r] = sp * (-expf(log_A[r]));
    }
  } else {
    int bid = blockIdx.x - 2048;
    const float* src; unsigned short* dst; int R, C, r0, c0, nkg;
    if (bid < 1024) { src = W1; dst = W1t; R = 1024; C = 4096; nkg = 32;
                      c0 = (bid & 63) * 64; r0 = (bid >> 6) * 64; }
    else { bid -= 1024; src = W2; dst = W2t; R = 4096; C = 1024; nkg = 128;
           c0 = (bid & 15) * 64; r0 = (bid >> 4) * 64; }
    #pragma unroll
    for (int q = 0; q < 4; ++q) {
      int lin = q * 256 + tid;
      int r = lin >> 4, cq = lin & 15;
      float4 v = *(const float4*)(src + (size_t)(r0 + r) * C + c0 + cq * 4);
      smem[r * 65 + cq * 4 + 0] = v.x; smem[r * 65 + cq * 4 + 1] = v.y;
      smem[r * 65 + cq * 4 + 2] = v.z; smem[r * 65 + cq * 4 + 3] = v.w;
    }
    __syncthreads();
    #pragma unroll
    for (int q = 0; q < 4; ++q) {
      int lin = q * 256 + tid;
      int c = lin >> 4, rq = lin & 15;
      ushort4 o;
      o.x = f2bf(smem[(rq * 4 + 0) * 65 + c]);
      o.y = f2bf(smem[(rq * 4 + 1) * 65 + c]);
      o.z = f2bf(smem[(rq * 4 + 2) * 65 + c]);
      o.w = f2bf(smem[(rq * 4 + 3) * 65 + c]);
      int n = c0 + c, k = r0 + rq * 4;
      int nt = n >> 4, l15n = n & 15;
      int kg = k >> 5, qd = (k >> 3) & 3, j0 = k & 7;
      *(ushort4*)(dst + ((size_t)(nt * nkg + kg)) * 512 + qd * 128 + l15n * 8 + j0) = o;
    }
  }
}

// ---- chunked scan (+ PASS1: out = ssm + bb2 init) ----
template <int PASS>
__global__ __launch_bounds__(256) void k_scan_pass(
    const float* __restrict__ xn, const float* __restrict__ x,
    const float* __restrict__ loga, float4* __restrict__ E, float* __restrict__ P,
    float* __restrict__ ssm, const float* __restrict__ bb2, float* __restrict__ out) {
  int bx = blockIdx.x;
  int b = bx >> 8, r = (bx >> 3) & 31, ch = bx & 7;
  int tid = threadIdx.x, cg = tid & 7, sub = tid >> 3;
  __shared__ float dec[128];
  __shared__ float4 sE[32][8];
  __shared__ float sP[32];
  if (tid < 128)
    dec[tid] = expf(loga[(size_t)(b * 1024 + ch * 128 + tid) * 32 + r]);
  __syncthreads();
  int t0 = ch * 128 + sub * 4;
  size_t base = ((size_t)(b * 1024 + t0) * 1024 + r * 32 + cg * 4) >> 2;
  const float4* xn4 = (const float4*)xn;
  float4 xv[4];
  #pragma unroll
  for (int i = 0; i < 4; ++i) xv[i] = xn4[base + (size_t)i * 256];
  float4 S = {0.f, 0.f, 0.f, 0.f};
  float Pl = 1.0f;
  #pragma unroll
  for (int i = 0; i < 4; ++i) {
    float d = dec[sub * 4 + i];
    S.x = d * S.x + xv[i].x; S.y = d * S.y + xv[i].y;
    S.z = d * S.z + xv[i].z; S.w = d * S.w + xv[i].w;
    Pl *= d;
  }
  sE[sub][cg] = S;
  if (cg == 0) sP[sub] = Pl;
  __syncthreads();
  if (PASS == 0) {
    if (tid < 8) {
      float4 Et = {0.f, 0.f, 0.f, 0.f};
      float PP = 1.0f;
      #pragma unroll
      for (int h = 0; h < 32; ++h) {
        float p = sP[h]; float4 e = sE[h][tid];
        Et.x = p * Et.x + e.x; Et.y = p * Et.y + e.y;
        Et.z = p * Et.z + e.z; Et.w = p * Et.w + e.w;
        PP *= p;
      }
      E[((size_t)(b * 32 + r) * 8 + ch) * 8 + tid] = Et;
      if (tid == 0) P[(b * 32 + r) * 8 + ch] = PP;
    }
  } else {
    float4 Sin = {0.f, 0.f, 0.f, 0.f};
    const float4* Eb = E + (size_t)(b * 32 + r) * 64 + cg;
    const float* Pb = P + (size_t)(b * 32 + r) * 8;
    for (int h = 0; h < ch; ++h) {
      float p = Pb[h]; float4 e = Eb[h * 8];
      Sin.x = p * Sin.x + e.x; Sin.y = p * Sin.y + e.y;
      Sin.z = p * Sin.z + e.z; Sin.w = p * Sin.w + e.w;
    }
    for (int h = 0; h < sub; ++h) {
      float p = sP[h]; float4 e = sE[h][cg];
      Sin.x = p * Sin.x + e.x; Sin.y = p * Sin.y + e.y;
      Sin.z = p * Sin.z + e.z; Sin.w = p * Sin.w + e.w;
    }
    float4 bb = ((const float4*)bb2)[r * 8 + cg];
    const float4* x4 = (const float4*)x;
    float4* ssm4 = (float4*)ssm;
    float4* out4 = (float4*)out;
    #pragma unroll
    for (int i = 0; i < 4; ++i) {
      float d = dec[sub * 4 + i];
      Sin.x = d * Sin.x + xv[i].x; Sin.y = d * Sin.y + xv[i].y;
      Sin.z = d * Sin.z + xv[i].z; Sin.w = d * Sin.w + xv[i].w;
      float4 rx = x4[base + (size_t)i * 256];
      float4 o;
      o.x = Sin.x + rx.x; o.y = Sin.y + rx.y;
      o.z = Sin.z + rx.z; o.w = Sin.w + rx.w;
      ssm4[base + (size_t)i * 256] = o;
      float4 oi;
      oi.x = o.x + bb.x; oi.y = o.y + bb.y; oi.z = o.z + bb.z; oi.w = o.w + bb.w;
      out4[base + (size_t)i * 256] = oi;
    }
  }
}

// ---- LN2 -> fn (bf16, A-packed for GEMM1: NKG=32) ----
__global__ __launch_bounds__(256) void k_ln2(
    const float* __restrict__ ssm, const float* __restrict__ g, const float* __restrict__ bta,
    unsigned short* __restrict__ fn) {
  int bs = blockIdx.x;
  int t = threadIdx.x;
  float4 v = ((const float4*)(ssm + (size_t)bs * 1024))[t];
  float s = v.x + v.y + v.z + v.w;
  float ss = v.x * v.x + v.y * v.y + v.z * v.z + v.w * v.w;
  #pragma unroll
  for (int o = 1; o < 64; o <<= 1) { s += __shfl_xor(s, o); ss += __shfl_xor(ss, o); }
  __shared__ float red[8];
  int w = t >> 6;
  if ((t & 63) == 0) { red[w] = s; red[4 + w] = ss; }
  __syncthreads();
  float S = red[0] + red[1] + red[2] + red[3];
  float SS = red[4] + red[5] + red[6] + red[7];
  float m = S * (1.0f / 1024.0f);
  float var = SS * (1.0f / 1024.0f) - m * m;
  float inv = rsqrtf(var + EPSF);
  float4 gv = ((const float4*)g)[t];
  float4 bv = ((const float4*)bta)[t];
  ushort4 o;
  o.x = f2bf((v.x - m) * inv * gv.x + bv.x);
  o.y = f2bf((v.y - m) * inv * gv.y + bv.y);
  o.z = f2bf((v.z - m) * inv * gv.z + bv.z);
  o.w = f2bf((v.w - m) * inv * gv.w + bv.w);
  // packed A write: row=bs, k = 4t..4t+3
  int mt = bs >> 4, l15m = bs & 15;
  int kg = t >> 3, qd = (t >> 1) & 3, j0 = (t & 1) * 4;
  *(ushort4*)(fn + ((size_t)(mt * 32 + kg)) * 512 + qd * 128 + l15m * 8 + j0) = o;
}

// ---- PACKED direct-load bf16 MFMA GEMM: no LDS, no barriers.
// 128x128 block, 4 waves (2x2) of 64x64; each fragment load = contiguous 1KB.
// EPI 0: hbf(A-packed for GEMM2, NKG=128) = gelu(acc+bias). EPI 1: atomicAdd fp32.
template <int EPI, int K, int KS>
__global__ __launch_bounds__(256) void k_gemm_p(
    const unsigned short* __restrict__ Ap, const unsigned short* __restrict__ Bp,
    const float* __restrict__ bias, void* __restrict__ C, int M, int N) {
  constexpr int NKG = K / 32;
  constexpr int ITER = K / KS / 32;      // 32 for both GEMMs
  int m0 = blockIdx.y * 128, n0 = blockIdx.x * 128;
  int kg0 = (KS > 1) ? ((int)blockIdx.z * ITER) : 0;
  int tid = threadIdx.x;
  int wave = tid >> 6, lane = tid & 63;
  int wr = wave >> 1, wc = wave & 1;
  int l15 = lane & 15, quad = lane >> 4;
  int mt0 = (m0 >> 4) + wr * 4;
  int nt0 = (n0 >> 4) + wc * 4;
  const unsigned short* pa = Ap + ((size_t)mt0 * NKG + kg0) * 512 + lane * 8;
  const unsigned short* pb = Bp + ((size_t)nt0 * NKG + kg0) * 512 + lane * 8;

  f32x4 zero = {0.0f, 0.0f, 0.0f, 0.0f};
  f32x4 acc[4][4];
  #pragma unroll
  for (int i = 0; i < 4; ++i)
    #pragma unroll
    for (int j = 0; j < 4; ++j) acc[i][j] = zero;

  bf16x8 a0[4], b0[4], a1[4], b1[4];
  #pragma unroll
  for (int i = 0; i < 4; ++i) {
    a0[i] = *(const bf16x8*)(pa + (size_t)i * NKG * 512);
    b0[i] = *(const bf16x8*)(pb + (size_t)i * NKG * 512);
  }
  #pragma unroll 1
  for (int kg = 0; kg < ITER; kg += 2) {
    #pragma unroll
    for (int i = 0; i < 4; ++i) {
      a1[i] = *(const bf16x8*)(pa + (size_t)i * NKG * 512 + (kg + 1) * 512);
      b1[i] = *(const bf16x8*)(pb + (size_t)i * NKG * 512 + (kg + 1) * 512);
    }
    #pragma unroll
    for (int i = 0; i < 4; ++i)
      #pragma unroll
      for (int j = 0; j < 4; ++j)
        acc[i][j] = __builtin_amdgcn_mfma_f32_16x16x32_bf16(a0[i], b0[j], acc[i][j], 0, 0, 0);
    if (kg + 2 < ITER) {
      #pragma unroll
      for (int i = 0; i < 4; ++i) {
        a0[i] = *(const bf16x8*)(pa + (size_t)i * NKG * 512 + (kg + 2) * 512);
        b0[i] = *(const bf16x8*)(pb + (size_t)i * NKG * 512 + (kg + 2) * 512);
      }
    }
    #pragma unroll
    for (int i = 0; i < 4; ++i)
      #pragma unroll
      for (int j = 0; j < 4; ++j)
        acc[i][j] = __builtin_amdgcn_mfma_f32_16x16x32_bf16(a1[i], b1[j], acc[i][j], 0, 0, 0);
  }

  if (EPI == 0) {
    unsigned short* Cb = (unsigned short*)C;   // A-packed for GEMM2 (NKG2=128)
    #pragma unroll
    for (int i = 0; i < 4; ++i) {
      int mt2 = (m0 + wr * 64 + i * 16) >> 4;
      #pragma unroll
      for (int j = 0; j < 4; ++j) {
        int col = n0 + wc * 64 + j * 16 + l15;   // = k of GEMM2
        float bval = bias[col];
        int kg2 = col >> 5, q2 = (col >> 3) & 3, j2 = col & 7;
        unsigned short* dst =
            Cb + ((size_t)(mt2 * 128 + kg2)) * 512 + q2 * 128 + j2;
        #pragma unroll
        for (int v = 0; v < 4; ++v) {
          float val = acc[i][j][v] + bval;
          val = 0.5f * val * (1.0f + erff(val * 0.70710678118654752f));
          dst[(quad * 4 + v) * 8] = f2bf(val);
        }
      }
    }
  } else {
    float* O = (float*)C;
    #pragma unroll
    for (int i = 0; i < 4; ++i)
      #pragma unroll
      for (int j = 0; j < 4; ++j) {
        int col = n0 + wc * 64 + j * 16 + l15;
        #pragma unroll
        for (int v = 0; v < 4; ++v) {
          int row = m0 + wr * 64 + i * 16 + quad * 4 + v;
          atomicAdd(&O[(size_t)row * N + col], acc[i][j][v]);
        }
      }
  }
}

extern "C" void kernel_launch(void* const* d_in, const int* in_sizes, int n_in,
                              void* d_out, int out_size, void* d_ws, size_t ws_size,
                              hipStream_t stream) {
  const float* x     = (const float*)d_in[0];
  const float* log_A = (const float*)d_in[1];
  const float* w_dt  = (const float*)d_in[2];
  const float* b_dt  = (const float*)d_in[3];
  const float* g_ssm = (const float*)d_in[4];
  const float* b_ssm = (const float*)d_in[5];
  const float* g_ffn = (const float*)d_in[6];
  const float* b_ffn = (const float*)d_in[7];
  const float* W1    = (const float*)d_in[8];
  const float* bb1   = (const float*)d_in[9];
  const float* W2    = (const float*)d_in[10];
  const float* bb2   = (const float*)d_in[11];
  float* out = (float*)d_out;

  const size_t MB = 1u << 20;
  char* ws = (char*)d_ws;
  float* xn            = (float*)(ws);                       // 0-8
  unsigned short* W1t  = (unsigned short*)(ws + 8 * MB);     // 8-16 (packed)
  float* loga          = (float*)(ws + 16 * MB);
  float4* Ebuf         = (float4*)(ws + 16 * MB + 262144);
  float* Pbuf          = (float*)(ws + 16 * MB + 393216);
  unsigned short* fn   = (unsigned short*)(ws + 17 * MB);    // 17-21 (packed)
  unsigned short* W2t  = (unsigned short*)(ws + 21 * MB);    // 21-29 (packed)
  float* ssm           = (float*)(ws + 29 * MB);             // 29-37
  unsigned short* hbf  = (unsigned short*)(ws + 37 * MB);    // 37-53 (packed)

  k_pre<<<4096, 256, 0, stream>>>(x, g_ssm, b_ssm, w_dt, b_dt, log_A, xn, loga,
                                  W1, W1t, W2, W2t);
  k_scan_pass<0><<<512, 256, 0, stream>>>(xn, x, loga, Ebuf, Pbuf, ssm, bb2, out);
  k_scan_pass<1><<<512, 256, 0, stream>>>(xn, x, loga, Ebuf, Pbuf, ssm, bb2, out);
  k_ln2<<<2048, 256, 0, stream>>>(ssm, g_ffn, b_ffn, fn);
  // GEMM1: 128x128 tiles, grid 32x16 = 512 blocks, K=1024
  k_gemm_p<0, 1024, 1><<<dim3(32, 16, 1), 256, 0, stream>>>(
      fn, W1t, bb1, (void*)hbf, 2048, 4096);
  // GEMM2: 128x128 tiles, split-K=4, atomic accumulate into out
  k_gemm_p<1, 4096, 4><<<dim3(8, 16, 4), 256, 0, stream>>>(
      hbf, W2t, nullptr, (void*)out, 2048, 1024);
}

// Round 8
// 196.629 us; speedup vs baseline: 1.3938x; 1.0430x over previous
//
#include <hip/hip_runtime.h>
#include <math.h>

#define EPSF 1e-5f

typedef __attribute__((ext_vector_type(8))) __bf16 bf16x8;
typedef __attribute__((ext_vector_type(4))) float f32x4;

__device__ __forceinline__ unsigned short f2bf(float f) {
  unsigned int u = __float_as_uint(f);
  u += 0x7FFFu + ((u >> 16) & 1u);
  return (unsigned short)(u >> 16);
}

// Packed fragment-major layout for MFMA operands:
//   element (row, k) lives at  ((rowTile*NKG + kg)*512 + quad*128 + (row&15)*8 + (k&7))
//   where rowTile=row>>4, kg=k>>5, quad=(k>>3)&3.
// A wave's 16x32 fragment = one contiguous 1KB block (lane*16B), fully coalesced.

// ---- fused: LN1+dt (blocks 0..2047) | weight transpose+pack (2048..4095) ----
__global__ __launch_bounds__(256) void k_pre(
    const float* __restrict__ x, const float* __restrict__ g, const float* __restrict__ bta,
    const float* __restrict__ w_dt, const float* __restrict__ b_dt,
    const float* __restrict__ log_A, float* __restrict__ xn, float* __restrict__ log_a,
    const float* __restrict__ W1, unsigned short* __restrict__ W1t,
    const float* __restrict__ W2, unsigned short* __restrict__ W2t) {
  __shared__ float smem[64 * 65];
  int tid = threadIdx.x;
  if (blockIdx.x < 2048) {
    int bs = blockIdx.x;
    int t = tid;
    float4 v = ((const float4*)(x + (size_t)bs * 1024))[t];
    float s = v.x + v.y + v.z + v.w;
    float ss = v.x * v.x + v.y * v.y + v.z * v.z + v.w * v.w;
    #pragma unroll
    for (int o = 1; o < 64; o <<= 1) { s += __shfl_xor(s, o); ss += __shfl_xor(ss, o); }
    float* red = smem;
    int w = t >> 6;
    if ((t & 63) == 0) { red[w] = s; red[4 + w] = ss; }
    __syncthreads();
    float S = red[0] + red[1] + red[2] + red[3];
    float SS = red[4] + red[5] + red[6] + red[7];
    float m = S * (1.0f / 1024.0f);
    float var = SS * (1.0f / 1024.0f) - m * m;
    float inv = rsqrtf(var + EPSF);
    float4 gv = ((const float4*)g)[t];
    float4 bv = ((const float4*)bta)[t];
    float4 o;
    o.x = (v.x - m) * inv * gv.x + bv.x;
    o.y = (v.y - m) * inv * gv.y + bv.y;
    o.z = (v.z - m) * inv * gv.z + bv.z;
    o.w = (v.w - m) * inv * gv.w + bv.w;
    ((float4*)(xn + (size_t)bs * 1024))[t] = o;
    float4 wv = ((const float4*)w_dt)[t & 7];
    float part = o.x * wv.x + o.y * wv.y + o.z * wv.z + o.w * wv.w;
    part += __shfl_xor(part, 1);
    part += __shfl_xor(part, 2);
    part += __shfl_xor(part, 4);
    if ((t & 7) == 0) {
      int r = t >> 3;
      float z = part + b_dt[0];
      float sp = (z > 20.0f) ? z : log1pf(expf(z));
      log_a[(size_t)bs * 32 + r] = sp * (-expf(log_A[r]));
    }
  } else {
    int bid = blockIdx.x - 2048;
    const float* src; unsigned short* dst; int R, C, r0, c0, nkg;
    if (bid < 1024) { src = W1; dst = W1t; R = 1024; C = 4096; nkg = 32;
                      c0 = (bid & 63) * 64; r0 = (bid >> 6) * 64; }
    else { bid -= 1024; src = W2; dst = W2t; R = 4096; C = 1024; nkg = 128;
           c0 = (bid & 15) * 64; r0 = (bid >> 4) * 64; }
    #pragma unroll
    for (int q = 0; q < 4; ++q) {
      int lin = q * 256 + tid;
      int r = lin >> 4, cq = lin & 15;
      float4 v = *(const float4*)(src + (size_t)(r0 + r) * C + c0 + cq * 4);
      smem[r * 65 + cq * 4 + 0] = v.x; smem[r * 65 + cq * 4 + 1] = v.y;
      smem[r * 65 + cq * 4 + 2] = v.z; smem[r * 65 + cq * 4 + 3] = v.w;
    }
    __syncthreads();
    #pragma unroll
    for (int q = 0; q < 4; ++q) {
      int lin = q * 256 + tid;
      int c = lin >> 4, rq = lin & 15;
      ushort4 o;
      o.x = f2bf(smem[(rq * 4 + 0) * 65 + c]);
      o.y = f2bf(smem[(rq * 4 + 1) * 65 + c]);
      o.z = f2bf(smem[(rq * 4 + 2) * 65 + c]);
      o.w = f2bf(smem[(rq * 4 + 3) * 65 + c]);
      int n = c0 + c, k = r0 + rq * 4;
      int nt = n >> 4, l15n = n & 15;
      int kg = k >> 5, qd = (k >> 3) & 3, j0 = k & 7;
      *(ushort4*)(dst + ((size_t)(nt * nkg + kg)) * 512 + qd * 128 + l15n * 8 + j0) = o;
    }
  }
}

// ---- chunked scan (+ PASS1: out = ssm + bb2 init) ----
template <int PASS>
__global__ __launch_bounds__(256) void k_scan_pass(
    const float* __restrict__ xn, const float* __restrict__ x,
    const float* __restrict__ loga, float4* __restrict__ E, float* __restrict__ P,
    float* __restrict__ ssm, const float* __restrict__ bb2, float* __restrict__ out) {
  int bx = blockIdx.x;
  int b = bx >> 8, r = (bx >> 3) & 31, ch = bx & 7;
  int tid = threadIdx.x, cg = tid & 7, sub = tid >> 3;
  __shared__ float dec[128];
  __shared__ float4 sE[32][8];
  __shared__ float sP[32];
  if (tid < 128)
    dec[tid] = expf(loga[(size_t)(b * 1024 + ch * 128 + tid) * 32 + r]);
  __syncthreads();
  int t0 = ch * 128 + sub * 4;
  size_t base = ((size_t)(b * 1024 + t0) * 1024 + r * 32 + cg * 4) >> 2;
  const float4* xn4 = (const float4*)xn;
  float4 xv[4];
  #pragma unroll
  for (int i = 0; i < 4; ++i) xv[i] = xn4[base + (size_t)i * 256];
  float4 S = {0.f, 0.f, 0.f, 0.f};
  float Pl = 1.0f;
  #pragma unroll
  for (int i = 0; i < 4; ++i) {
    float d = dec[sub * 4 + i];
    S.x = d * S.x + xv[i].x; S.y = d * S.y + xv[i].y;
    S.z = d * S.z + xv[i].z; S.w = d * S.w + xv[i].w;
    Pl *= d;
  }
  sE[sub][cg] = S;
  if (cg == 0) sP[sub] = Pl;
  __syncthreads();
  if (PASS == 0) {
    if (tid < 8) {
      float4 Et = {0.f, 0.f, 0.f, 0.f};
      float PP = 1.0f;
      #pragma unroll
      for (int h = 0; h < 32; ++h) {
        float p = sP[h]; float4 e = sE[h][tid];
        Et.x = p * Et.x + e.x; Et.y = p * Et.y + e.y;
        Et.z = p * Et.z + e.z; Et.w = p * Et.w + e.w;
        PP *= p;
      }
      E[((size_t)(b * 32 + r) * 8 + ch) * 8 + tid] = Et;
      if (tid == 0) P[(b * 32 + r) * 8 + ch] = PP;
    }
  } else {
    float4 Sin = {0.f, 0.f, 0.f, 0.f};
    const float4* Eb = E + (size_t)(b * 32 + r) * 64 + cg;
    const float* Pb = P + (size_t)(b * 32 + r) * 8;
    for (int h = 0; h < ch; ++h) {
      float p = Pb[h]; float4 e = Eb[h * 8];
      Sin.x = p * Sin.x + e.x; Sin.y = p * Sin.y + e.y;
      Sin.z = p * Sin.z + e.z; Sin.w = p * Sin.w + e.w;
    }
    for (int h = 0; h < sub; ++h) {
      float p = sP[h]; float4 e = sE[h][cg];
      Sin.x = p * Sin.x + e.x; Sin.y = p * Sin.y + e.y;
      Sin.z = p * Sin.z + e.z; Sin.w = p * Sin.w + e.w;
    }
    float4 bb = ((const float4*)bb2)[r * 8 + cg];
    const float4* x4 = (const float4*)x;
    float4* ssm4 = (float4*)ssm;
    float4* out4 = (float4*)out;
    #pragma unroll
    for (int i = 0; i < 4; ++i) {
      float d = dec[sub * 4 + i];
      Sin.x = d * Sin.x + xv[i].x; Sin.y = d * Sin.y + xv[i].y;
      Sin.z = d * Sin.z + xv[i].z; Sin.w = d * Sin.w + xv[i].w;
      float4 rx = x4[base + (size_t)i * 256];
      float4 o;
      o.x = Sin.x + rx.x; o.y = Sin.y + rx.y;
      o.z = Sin.z + rx.z; o.w = Sin.w + rx.w;
      ssm4[base + (size_t)i * 256] = o;
      float4 oi;
      oi.x = o.x + bb.x; oi.y = o.y + bb.y; oi.z = o.z + bb.z; oi.w = o.w + bb.w;
      out4[base + (size_t)i * 256] = oi;
    }
  }
}

// ---- LN2 -> fn (bf16, A-packed for GEMM1: NKG=32) ----
__global__ __launch_bounds__(256) void k_ln2(
    const float* __restrict__ ssm, const float* __restrict__ g, const float* __restrict__ bta,
    unsigned short* __restrict__ fn) {
  int bs = blockIdx.x;
  int t = threadIdx.x;
  float4 v = ((const float4*)(ssm + (size_t)bs * 1024))[t];
  float s = v.x + v.y + v.z + v.w;
  float ss = v.x * v.x + v.y * v.y + v.z * v.z + v.w * v.w;
  #pragma unroll
  for (int o = 1; o < 64; o <<= 1) { s += __shfl_xor(s, o); ss += __shfl_xor(ss, o); }
  __shared__ float red[8];
  int w = t >> 6;
  if ((t & 63) == 0) { red[w] = s; red[4 + w] = ss; }
  __syncthreads();
  float S = red[0] + red[1] + red[2] + red[3];
  float SS = red[4] + red[5] + red[6] + red[7];
  float m = S * (1.0f / 1024.0f);
  float var = SS * (1.0f / 1024.0f) - m * m;
  float inv = rsqrtf(var + EPSF);
  float4 gv = ((const float4*)g)[t];
  float4 bv = ((const float4*)bta)[t];
  ushort4 o;
  o.x = f2bf((v.x - m) * inv * gv.x + bv.x);
  o.y = f2bf((v.y - m) * inv * gv.y + bv.y);
  o.z = f2bf((v.z - m) * inv * gv.z + bv.z);
  o.w = f2bf((v.w - m) * inv * gv.w + bv.w);
  // packed A write: row=bs, k = 4t..4t+3
  int mt = bs >> 4, l15m = bs & 15;
  int kg = t >> 3, qd = (t >> 1) & 3, j0 = (t & 1) * 4;
  *(ushort4*)(fn + ((size_t)(mt * 32 + kg)) * 512 + qd * 128 + l15m * 8 + j0) = o;
}

// ---- PACKED direct-load bf16 MFMA GEMM: no LDS, no barriers.
// 128x128 block, 4 waves (2x2) of 64x64; each fragment load = contiguous 1KB.
// 4-stage register pipeline, branch-free peeled tail (loads ~3 stages ahead).
// EPI 0: hbf(A-packed for GEMM2, NKG=128) = gelu(acc+bias). EPI 1: atomicAdd fp32.
template <int EPI, int K, int KS>
__global__ __launch_bounds__(256, 2) void k_gemm_p(
    const unsigned short* __restrict__ Ap, const unsigned short* __restrict__ Bp,
    const float* __restrict__ bias, void* __restrict__ C, int M, int N) {
  constexpr int NKG = K / 32;
  constexpr int ITER = K / KS / 32;      // 32 for both GEMMs (divisible by 4)
  int m0 = blockIdx.y * 128, n0 = blockIdx.x * 128;
  int kg0 = (KS > 1) ? ((int)blockIdx.z * ITER) : 0;
  int tid = threadIdx.x;
  int wave = tid >> 6, lane = tid & 63;
  int wr = wave >> 1, wc = wave & 1;
  int l15 = lane & 15, quad = lane >> 4;
  int mt0 = (m0 >> 4) + wr * 4;
  int nt0 = (n0 >> 4) + wc * 4;
  const unsigned short* pa = Ap + ((size_t)mt0 * NKG + kg0) * 512 + lane * 8;
  const unsigned short* pb = Bp + ((size_t)nt0 * NKG + kg0) * 512 + lane * 8;

  f32x4 zero = {0.0f, 0.0f, 0.0f, 0.0f};
  f32x4 acc[4][4];
  #pragma unroll
  for (int i = 0; i < 4; ++i)
    #pragma unroll
    for (int j = 0; j < 4; ++j) acc[i][j] = zero;

  bf16x8 a[4][4], b[4][4];
  #pragma unroll
  for (int s = 0; s < 4; ++s)
    #pragma unroll
    for (int i = 0; i < 4; ++i) {
      a[s][i] = *(const bf16x8*)(pa + ((size_t)i * NKG + s) * 512);
      b[s][i] = *(const bf16x8*)(pb + ((size_t)i * NKG + s) * 512);
    }

  #pragma unroll 1
  for (int kg = 0; kg < ITER - 4; kg += 4) {
    #pragma unroll
    for (int s = 0; s < 4; ++s) {
      #pragma unroll
      for (int i = 0; i < 4; ++i)
        #pragma unroll
        for (int j = 0; j < 4; ++j)
          acc[i][j] = __builtin_amdgcn_mfma_f32_16x16x32_bf16(a[s][i], b[s][j], acc[i][j], 0, 0, 0);
      #pragma unroll
      for (int i = 0; i < 4; ++i) {
        a[s][i] = *(const bf16x8*)(pa + ((size_t)i * NKG + kg + 4 + s) * 512);
        b[s][i] = *(const bf16x8*)(pb + ((size_t)i * NKG + kg + 4 + s) * 512);
      }
    }
  }
  #pragma unroll
  for (int s = 0; s < 4; ++s)
    #pragma unroll
    for (int i = 0; i < 4; ++i)
      #pragma unroll
      for (int j = 0; j < 4; ++j)
        acc[i][j] = __builtin_amdgcn_mfma_f32_16x16x32_bf16(a[s][i], b[s][j], acc[i][j], 0, 0, 0);

  if (EPI == 0) {
    unsigned short* Cb = (unsigned short*)C;   // A-packed for GEMM2 (NKG2=128)
    #pragma unroll
    for (int i = 0; i < 4; ++i) {
      int mt2 = (m0 + wr * 64 + i * 16) >> 4;
      #pragma unroll
      for (int j = 0; j < 4; ++j) {
        int col = n0 + wc * 64 + j * 16 + l15;   // = k of GEMM2
        float bval = bias[col];
        int kg2 = col >> 5, q2 = (col >> 3) & 3, j2 = col & 7;
        unsigned short* dst =
            Cb + ((size_t)(mt2 * 128 + kg2)) * 512 + q2 * 128 + j2;
        #pragma unroll
        for (int v = 0; v < 4; ++v) {
          float val = acc[i][j][v] + bval;
          val = 0.5f * val * (1.0f + erff(val * 0.70710678118654752f));
          dst[(quad * 4 + v) * 8] = f2bf(val);
        }
      }
    }
  } else {
    float* O = (float*)C;
    #pragma unroll
    for (int i = 0; i < 4; ++i)
      #pragma unroll
      for (int j = 0; j < 4; ++j) {
        int col = n0 + wc * 64 + j * 16 + l15;
        #pragma unroll
        for (int v = 0; v < 4; ++v) {
          int row = m0 + wr * 64 + i * 16 + quad * 4 + v;
          atomicAdd(&O[(size_t)row * N + col], acc[i][j][v]);
        }
      }
  }
}

extern "C" void kernel_launch(void* const* d_in, const int* in_sizes, int n_in,
                              void* d_out, int out_size, void* d_ws, size_t ws_size,
                              hipStream_t stream) {
  const float* x     = (const float*)d_in[0];
  const float* log_A = (const float*)d_in[1];
  const float* w_dt  = (const float*)d_in[2];
  const float* b_dt  = (const float*)d_in[3];
  const float* g_ssm = (const float*)d_in[4];
  const float* b_ssm = (const float*)d_in[5];
  const float* g_ffn = (const float*)d_in[6];
  const float* b_ffn = (const float*)d_in[7];
  const float* W1    = (const float*)d_in[8];
  const float* bb1   = (const float*)d_in[9];
  const float* W2    = (const float*)d_in[10];
  const float* bb2   = (const float*)d_in[11];
  float* out = (float*)d_out;

  const size_t MB = 1u << 20;
  char* ws = (char*)d_ws;
  float* xn            = (float*)(ws);                       // 0-8
  unsigned short* W1t  = (unsigned short*)(ws + 8 * MB);     // 8-16 (packed)
  float* loga          = (float*)(ws + 16 * MB);
  float4* Ebuf         = (float4*)(ws + 16 * MB + 262144);
  float* Pbuf          = (float*)(ws + 16 * MB + 393216);
  unsigned short* fn   = (unsigned short*)(ws + 17 * MB);    // 17-21 (packed)
  unsigned short* W2t  = (unsigned short*)(ws + 21 * MB);    // 21-29 (packed)
  float* ssm           = (float*)(ws + 29 * MB);             // 29-37
  unsigned short* hbf  = (unsigned short*)(ws + 37 * MB);    // 37-53 (packed)

  k_pre<<<4096, 256, 0, stream>>>(x, g_ssm, b_ssm, w_dt, b_dt, log_A, xn, loga,
                                  W1, W1t, W2, W2t);
  k_scan_pass<0><<<512, 256, 0, stream>>>(xn, x, loga, Ebuf, Pbuf, ssm, bb2, out);
  k_scan_pass<1><<<512, 256, 0, stream>>>(xn, x, loga, Ebuf, Pbuf, ssm, bb2, out);
  k_ln2<<<2048, 256, 0, stream>>>(ssm, g_ffn, b_ffn, fn);
  // GEMM1: 128x128 tiles, grid 32x16 = 512 blocks, K=1024
  k_gemm_p<0, 1024, 1><<<dim3(32, 16, 1), 256, 0, stream>>>(
      fn, W1t, bb1, (void*)hbf, 2048, 4096);
  // GEMM2: 128x128 tiles, split-K=4, atomic accumulate into out
  k_gemm_p<1, 4096, 4><<<dim3(8, 16, 4), 256, 0, stream>>>(
      hbf, W2t, nullptr, (void*)out, 2048, 1024);
}

// Round 9
// 193.421 us; speedup vs baseline: 1.4169x; 1.0166x over previous
//
#include <hip/hip_runtime.h>
#include <math.h>

#define EPSF 1e-5f

typedef __attribute__((ext_vector_type(8))) __bf16 bf16x8;
typedef __attribute__((ext_vector_type(4))) float f32x4;

__device__ __forceinline__ unsigned short f2bf(float f) {
  unsigned int u = __float_as_uint(f);
  u += 0x7FFFu + ((u >> 16) & 1u);
  return (unsigned short)(u >> 16);
}

// Packed fragment-major layout for MFMA operands:
//   element (row, k) lives at  ((rowTile*NKG + kg)*512 + quad*128 + (row&15)*8 + (k&7))
//   where rowTile=row>>4, kg=k>>5, quad=(k>>3)&3.
// A wave's 16x32 fragment = one contiguous 1KB block (lane*16B), fully coalesced.

// ---- fused: LN1+dt (blocks 0..2047) | weight transpose+pack (2048..4095) ----
__global__ __launch_bounds__(256) void k_pre(
    const float* __restrict__ x, const float* __restrict__ g, const float* __restrict__ bta,
    const float* __restrict__ w_dt, const float* __restrict__ b_dt,
    const float* __restrict__ log_A, float* __restrict__ xn, float* __restrict__ log_a,
    const float* __restrict__ W1, unsigned short* __restrict__ W1t,
    const float* __restrict__ W2, unsigned short* __restrict__ W2t) {
  __shared__ float smem[64 * 65];
  int tid = threadIdx.x;
  if (blockIdx.x < 2048) {
    int bs = blockIdx.x;
    int t = tid;
    float4 v = ((const float4*)(x + (size_t)bs * 1024))[t];
    float s = v.x + v.y + v.z + v.w;
    float ss = v.x * v.x + v.y * v.y + v.z * v.z + v.w * v.w;
    #pragma unroll
    for (int o = 1; o < 64; o <<= 1) { s += __shfl_xor(s, o); ss += __shfl_xor(ss, o); }
    float* red = smem;
    int w = t >> 6;
    if ((t & 63) == 0) { red[w] = s; red[4 + w] = ss; }
    __syncthreads();
    float S = red[0] + red[1] + red[2] + red[3];
    float SS = red[4] + red[5] + red[6] + red[7];
    float m = S * (1.0f / 1024.0f);
    float var = SS * (1.0f / 1024.0f) - m * m;
    float inv = rsqrtf(var + EPSF);
    float4 gv = ((const float4*)g)[t];
    float4 bv = ((const float4*)bta)[t];
    float4 o;
    o.x = (v.x - m) * inv * gv.x + bv.x;
    o.y = (v.y - m) * inv * gv.y + bv.y;
    o.z = (v.z - m) * inv * gv.z + bv.z;
    o.w = (v.w - m) * inv * gv.w + bv.w;
    ((float4*)(xn + (size_t)bs * 1024))[t] = o;
    float4 wv = ((const float4*)w_dt)[t & 7];
    float part = o.x * wv.x + o.y * wv.y + o.z * wv.z + o.w * wv.w;
    part += __shfl_xor(part, 1);
    part += __shfl_xor(part, 2);
    part += __shfl_xor(part, 4);
    if ((t & 7) == 0) {
      int r = t >> 3;
      float z = part + b_dt[0];
      float sp = (z > 20.0f) ? z : log1pf(expf(z));
      log_a[(size_t)bs * 32 + r] = sp * (-expf(log_A[r]));
    }
  } else {
    int bid = blockIdx.x - 2048;
    const float* src; unsigned short* dst; int R, C, r0, c0, nkg;
    if (bid < 1024) { src = W1; dst = W1t; R = 1024; C = 4096; nkg = 32;
                      c0 = (bid & 63) * 64; r0 = (bid >> 6) * 64; }
    else { bid -= 1024; src = W2; dst = W2t; R = 4096; C = 1024; nkg = 128;
           c0 = (bid & 15) * 64; r0 = (bid >> 4) * 64; }
    #pragma unroll
    for (int q = 0; q < 4; ++q) {
      int lin = q * 256 + tid;
      int r = lin >> 4, cq = lin & 15;
      float4 v = *(const float4*)(src + (size_t)(r0 + r) * C + c0 + cq * 4);
      smem[r * 65 + cq * 4 + 0] = v.x; smem[r * 65 + cq * 4 + 1] = v.y;
      smem[r * 65 + cq * 4 + 2] = v.z; smem[r * 65 + cq * 4 + 3] = v.w;
    }
    __syncthreads();
    #pragma unroll
    for (int q = 0; q < 4; ++q) {
      int lin = q * 256 + tid;
      int c = lin >> 4, rq = lin & 15;
      ushort4 o;
      o.x = f2bf(smem[(rq * 4 + 0) * 65 + c]);
      o.y = f2bf(smem[(rq * 4 + 1) * 65 + c]);
      o.z = f2bf(smem[(rq * 4 + 2) * 65 + c]);
      o.w = f2bf(smem[(rq * 4 + 3) * 65 + c]);
      int n = c0 + c, k = r0 + rq * 4;
      int nt = n >> 4, l15n = n & 15;
      int kg = k >> 5, qd = (k >> 3) & 3, j0 = k & 7;
      *(ushort4*)(dst + ((size_t)(nt * nkg + kg)) * 512 + qd * 128 + l15n * 8 + j0) = o;
    }
  }
}

// ---- chunked scan (+ PASS1: out = ssm + bb2 init) ----
template <int PASS>
__global__ __launch_bounds__(256) void k_scan_pass(
    const float* __restrict__ xn, const float* __restrict__ x,
    const float* __restrict__ loga, float4* __restrict__ E, float* __restrict__ P,
    float* __restrict__ ssm, const float* __restrict__ bb2, float* __restrict__ out) {
  int bx = blockIdx.x;
  int b = bx >> 8, r = (bx >> 3) & 31, ch = bx & 7;
  int tid = threadIdx.x, cg = tid & 7, sub = tid >> 3;
  __shared__ float dec[128];
  __shared__ float4 sE[32][8];
  __shared__ float sP[32];
  if (tid < 128)
    dec[tid] = expf(loga[(size_t)(b * 1024 + ch * 128 + tid) * 32 + r]);
  __syncthreads();
  int t0 = ch * 128 + sub * 4;
  size_t base = ((size_t)(b * 1024 + t0) * 1024 + r * 32 + cg * 4) >> 2;
  const float4* xn4 = (const float4*)xn;
  float4 xv[4];
  #pragma unroll
  for (int i = 0; i < 4; ++i) xv[i] = xn4[base + (size_t)i * 256];
  float4 S = {0.f, 0.f, 0.f, 0.f};
  float Pl = 1.0f;
  #pragma unroll
  for (int i = 0; i < 4; ++i) {
    float d = dec[sub * 4 + i];
    S.x = d * S.x + xv[i].x; S.y = d * S.y + xv[i].y;
    S.z = d * S.z + xv[i].z; S.w = d * S.w + xv[i].w;
    Pl *= d;
  }
  sE[sub][cg] = S;
  if (cg == 0) sP[sub] = Pl;
  __syncthreads();
  if (PASS == 0) {
    if (tid < 8) {
      float4 Et = {0.f, 0.f, 0.f, 0.f};
      float PP = 1.0f;
      #pragma unroll
      for (int h = 0; h < 32; ++h) {
        float p = sP[h]; float4 e = sE[h][tid];
        Et.x = p * Et.x + e.x; Et.y = p * Et.y + e.y;
        Et.z = p * Et.z + e.z; Et.w = p * Et.w + e.w;
        PP *= p;
      }
      E[((size_t)(b * 32 + r) * 8 + ch) * 8 + tid] = Et;
      if (tid == 0) P[(b * 32 + r) * 8 + ch] = PP;
    }
  } else {
    float4 Sin = {0.f, 0.f, 0.f, 0.f};
    const float4* Eb = E + (size_t)(b * 32 + r) * 64 + cg;
    const float* Pb = P + (size_t)(b * 32 + r) * 8;
    for (int h = 0; h < ch; ++h) {
      float p = Pb[h]; float4 e = Eb[h * 8];
      Sin.x = p * Sin.x + e.x; Sin.y = p * Sin.y + e.y;
      Sin.z = p * Sin.z + e.z; Sin.w = p * Sin.w + e.w;
    }
    for (int h = 0; h < sub; ++h) {
      float p = sP[h]; float4 e = sE[h][cg];
      Sin.x = p * Sin.x + e.x; Sin.y = p * Sin.y + e.y;
      Sin.z = p * Sin.z + e.z; Sin.w = p * Sin.w + e.w;
    }
    float4 bb = ((const float4*)bb2)[r * 8 + cg];
    const float4* x4 = (const float4*)x;
    float4* ssm4 = (float4*)ssm;
    float4* out4 = (float4*)out;
    #pragma unroll
    for (int i = 0; i < 4; ++i) {
      float d = dec[sub * 4 + i];
      Sin.x = d * Sin.x + xv[i].x; Sin.y = d * Sin.y + xv[i].y;
      Sin.z = d * Sin.z + xv[i].z; Sin.w = d * Sin.w + xv[i].w;
      float4 rx = x4[base + (size_t)i * 256];
      float4 o;
      o.x = Sin.x + rx.x; o.y = Sin.y + rx.y;
      o.z = Sin.z + rx.z; o.w = Sin.w + rx.w;
      ssm4[base + (size_t)i * 256] = o;
      float4 oi;
      oi.x = o.x + bb.x; oi.y = o.y + bb.y; oi.z = o.z + bb.z; oi.w = o.w + bb.w;
      out4[base + (size_t)i * 256] = oi;
    }
  }
}

// ---- LN2 -> fn (bf16, A-packed for GEMM1: NKG=32) ----
__global__ __launch_bounds__(256) void k_ln2(
    const float* __restrict__ ssm, const float* __restrict__ g, const float* __restrict__ bta,
    unsigned short* __restrict__ fn) {
  int bs = blockIdx.x;
  int t = threadIdx.x;
  float4 v = ((const float4*)(ssm + (size_t)bs * 1024))[t];
  float s = v.x + v.y + v.z + v.w;
  float ss = v.x * v.x + v.y * v.y + v.z * v.z + v.w * v.w;
  #pragma unroll
  for (int o = 1; o < 64; o <<= 1) { s += __shfl_xor(s, o); ss += __shfl_xor(ss, o); }
  __shared__ float red[8];
  int w = t >> 6;
  if ((t & 63) == 0) { red[w] = s; red[4 + w] = ss; }
  __syncthreads();
  float S = red[0] + red[1] + red[2] + red[3];
  float SS = red[4] + red[5] + red[6] + red[7];
  float m = S * (1.0f / 1024.0f);
  float var = SS * (1.0f / 1024.0f) - m * m;
  float inv = rsqrtf(var + EPSF);
  float4 gv = ((const float4*)g)[t];
  float4 bv = ((const float4*)bta)[t];
  ushort4 o;
  o.x = f2bf((v.x - m) * inv * gv.x + bv.x);
  o.y = f2bf((v.y - m) * inv * gv.y + bv.y);
  o.z = f2bf((v.z - m) * inv * gv.z + bv.z);
  o.w = f2bf((v.w - m) * inv * gv.w + bv.w);
  // packed A write: row=bs, k = 4t..4t+3
  int mt = bs >> 4, l15m = bs & 15;
  int kg = t >> 3, qd = (t >> 1) & 3, j0 = (t & 1) * 4;
  *(ushort4*)(fn + ((size_t)(mt * 32 + kg)) * 512 + qd * 128 + l15m * 8 + j0) = o;
}

// ---- PACKED direct-load bf16 MFMA GEMM: no LDS, no barriers.
// 128x128 block, 4 waves (2x2) of 64x64; fragment load = contiguous 1KB.
// 4-stage register pipeline, branch-free peeled tail.
// XCD-aware 1-D grid decode (L&7 = XCD): per-XCD operand set fits 4MB L2.
// EPI 0: hbf(A-packed for GEMM2, NKG=128) = gelu(acc+bias). EPI 1: atomicAdd fp32.
template <int EPI, int K, int KS>
__global__ __launch_bounds__(256, 2) void k_gemm_p(
    const unsigned short* __restrict__ Ap, const unsigned short* __restrict__ Bp,
    const float* __restrict__ bias, void* __restrict__ C, int M, int N) {
  constexpr int NKG = K / 32;
  constexpr int ITER = K / KS / 32;      // 32 for both GEMMs (divisible by 4)
  int L = blockIdx.x;
  int m0, n0, kg0;
  if (EPI == 0) {
    // 512 blocks: xcd=(n_quad[2b], m_half[1b]); rest: nx[3b], my[3b]
    int xcd = L & 7;
    int nq = xcd & 3, mh = xcd >> 2;
    int rest = L >> 3;
    int nx = rest & 7, my = rest >> 3;
    n0 = (nq * 8 + nx) * 128;            // 32 n-tiles
    m0 = (mh * 8 + my) * 128;            // 16 m-tiles
    kg0 = 0;
  } else {
    // 512 blocks: xcd=(ks[2b], m_half[1b]); rest: nx[3b], my[3b]
    int xcd = L & 7;
    int ks = xcd >> 1, mh = xcd & 1;
    int rest = L >> 3;
    int nx = rest & 7, my = rest >> 3;
    n0 = nx * 128;                       // 8 n-tiles
    m0 = (mh * 8 + my) * 128;            // 16 m-tiles
    kg0 = ks * ITER;
  }
  int tid = threadIdx.x;
  int wave = tid >> 6, lane = tid & 63;
  int wr = wave >> 1, wc = wave & 1;
  int l15 = lane & 15, quad = lane >> 4;
  int mt0 = (m0 >> 4) + wr * 4;
  int nt0 = (n0 >> 4) + wc * 4;
  const unsigned short* pa = Ap + ((size_t)mt0 * NKG + kg0) * 512 + lane * 8;
  const unsigned short* pb = Bp + ((size_t)nt0 * NKG + kg0) * 512 + lane * 8;

  f32x4 zero = {0.0f, 0.0f, 0.0f, 0.0f};
  f32x4 acc[4][4];
  #pragma unroll
  for (int i = 0; i < 4; ++i)
    #pragma unroll
    for (int j = 0; j < 4; ++j) acc[i][j] = zero;

  bf16x8 a[4][4], b[4][4];
  #pragma unroll
  for (int s = 0; s < 4; ++s)
    #pragma unroll
    for (int i = 0; i < 4; ++i) {
      a[s][i] = *(const bf16x8*)(pa + ((size_t)i * NKG + s) * 512);
      b[s][i] = *(const bf16x8*)(pb + ((size_t)i * NKG + s) * 512);
    }

  #pragma unroll 1
  for (int kg = 0; kg < ITER - 4; kg += 4) {
    #pragma unroll
    for (int s = 0; s < 4; ++s) {
      #pragma unroll
      for (int i = 0; i < 4; ++i)
        #pragma unroll
        for (int j = 0; j < 4; ++j)
          acc[i][j] = __builtin_amdgcn_mfma_f32_16x16x32_bf16(a[s][i], b[s][j], acc[i][j], 0, 0, 0);
      #pragma unroll
      for (int i = 0; i < 4; ++i) {
        a[s][i] = *(const bf16x8*)(pa + ((size_t)i * NKG + kg + 4 + s) * 512);
        b[s][i] = *(const bf16x8*)(pb + ((size_t)i * NKG + kg + 4 + s) * 512);
      }
    }
  }
  #pragma unroll
  for (int s = 0; s < 4; ++s)
    #pragma unroll
    for (int i = 0; i < 4; ++i)
      #pragma unroll
      for (int j = 0; j < 4; ++j)
        acc[i][j] = __builtin_amdgcn_mfma_f32_16x16x32_bf16(a[s][i], b[s][j], acc[i][j], 0, 0, 0);

  if (EPI == 0) {
    unsigned short* Cb = (unsigned short*)C;   // A-packed for GEMM2 (NKG2=128)
    #pragma unroll
    for (int i = 0; i < 4; ++i) {
      int mt2 = (m0 + wr * 64 + i * 16) >> 4;
      #pragma unroll
      for (int j = 0; j < 4; ++j) {
        int col = n0 + wc * 64 + j * 16 + l15;   // = k of GEMM2
        float bval = bias[col];
        int kg2 = col >> 5, q2 = (col >> 3) & 3, j2 = col & 7;
        unsigned short* dst =
            Cb + ((size_t)(mt2 * 128 + kg2)) * 512 + q2 * 128 + j2;
        #pragma unroll
        for (int v = 0; v < 4; ++v) {
          float val = acc[i][j][v] + bval;
          val = 0.5f * val * (1.0f + erff(val * 0.70710678118654752f));
          dst[(quad * 4 + v) * 8] = f2bf(val);
        }
      }
    }
  } else {
    float* O = (float*)C;
    #pragma unroll
    for (int i = 0; i < 4; ++i)
      #pragma unroll
      for (int j = 0; j < 4; ++j) {
        int col = n0 + wc * 64 + j * 16 + l15;
        #pragma unroll
        for (int v = 0; v < 4; ++v) {
          int row = m0 + wr * 64 + i * 16 + quad * 4 + v;
          atomicAdd(&O[(size_t)row * N + col], acc[i][j][v]);
        }
      }
  }
}

extern "C" void kernel_launch(void* const* d_in, const int* in_sizes, int n_in,
                              void* d_out, int out_size, void* d_ws, size_t ws_size,
                              hipStream_t stream) {
  const float* x     = (const float*)d_in[0];
  const float* log_A = (const float*)d_in[1];
  const float* w_dt  = (const float*)d_in[2];
  const float* b_dt  = (const float*)d_in[3];
  const float* g_ssm = (const float*)d_in[4];
  const float* b_ssm = (const float*)d_in[5];
  const float* g_ffn = (const float*)d_in[6];
  const float* b_ffn = (const float*)d_in[7];
  const float* W1    = (const float*)d_in[8];
  const float* bb1   = (const float*)d_in[9];
  const float* W2    = (const float*)d_in[10];
  const float* bb2   = (const float*)d_in[11];
  float* out = (float*)d_out;

  const size_t MB = 1u << 20;
  char* ws = (char*)d_ws;
  float* xn            = (float*)(ws);                       // 0-8
  unsigned short* W1t  = (unsigned short*)(ws + 8 * MB);     // 8-16 (packed)
  float* loga          = (float*)(ws + 16 * MB);
  float4* Ebuf         = (float4*)(ws + 16 * MB + 262144);
  float* Pbuf          = (float*)(ws + 16 * MB + 393216);
  unsigned short* fn   = (unsigned short*)(ws + 17 * MB);    // 17-21 (packed)
  unsigned short* W2t  = (unsigned short*)(ws + 21 * MB);    // 21-29 (packed)
  float* ssm           = (float*)(ws + 29 * MB);             // 29-37
  unsigned short* hbf  = (unsigned short*)(ws + 37 * MB);    // 37-53 (packed)

  k_pre<<<4096, 256, 0, stream>>>(x, g_ssm, b_ssm, w_dt, b_dt, log_A, xn, loga,
                                  W1, W1t, W2, W2t);
  k_scan_pass<0><<<512, 256, 0, stream>>>(xn, x, loga, Ebuf, Pbuf, ssm, bb2, out);
  k_scan_pass<1><<<512, 256, 0, stream>>>(xn, x, loga, Ebuf, Pbuf, ssm, bb2, out);
  k_ln2<<<2048, 256, 0, stream>>>(ssm, g_ffn, b_ffn, fn);
  // GEMM1: XCD-decoded 1-D grid, 512 blocks, K=1024
  k_gemm_p<0, 1024, 1><<<512, 256, 0, stream>>>(
      fn, W1t, bb1, (void*)hbf, 2048, 4096);
  // GEMM2: XCD-decoded 1-D grid, 512 blocks, split-K=4, atomic accumulate
  k_gemm_p<1, 4096, 4><<<512, 256, 0, stream>>>(
      hbf, W2t, nullptr, (void*)out, 2048, 1024);
}

// Round 10
// 189.710 us; speedup vs baseline: 1.4446x; 1.0196x over previous
//
#include <hip/hip_runtime.h>
#include <math.h>

#define EPSF 1e-5f

typedef __attribute__((ext_vector_type(8))) __bf16 bf16x8;
typedef __attribute__((ext_vector_type(4))) float f32x4;

__device__ __forceinline__ unsigned short f2bf(float f) {
  unsigned int u = __float_as_uint(f);
  u += 0x7FFFu + ((u >> 16) & 1u);
  return (unsigned short)(u >> 16);
}
__device__ __forceinline__ float bf2f(unsigned short u) {
  return __uint_as_float((unsigned int)u << 16);
}

// Packed fragment-major layout (element size E bytes):
//   (row, k) -> ((row>>4)*NKG + (k>>5))*512E + ((k>>3)&3)*128E + (row&15)*8E + (k&7)*E
// A wave's 16x32 fragment = contiguous (lane*8E) block, fully coalesced.

// ---- fused: LN1+dt (0..2047) | W1 pack bf16 (2048..3071) | W2 pack fp8x16 (3072..4095)
__global__ __launch_bounds__(256) void k_pre(
    const float* __restrict__ x, const float* __restrict__ g, const float* __restrict__ bta,
    const float* __restrict__ w_dt, const float* __restrict__ b_dt,
    const float* __restrict__ log_A, unsigned short* __restrict__ xn, float* __restrict__ log_a,
    const float* __restrict__ W1, unsigned short* __restrict__ W1t,
    const float* __restrict__ W2, unsigned char* __restrict__ W2t) {
  __shared__ float smem[64 * 65];
  int tid = threadIdx.x;
  if (blockIdx.x < 2048) {
    int bs = blockIdx.x;
    int t = tid;
    float4 v = ((const float4*)(x + (size_t)bs * 1024))[t];
    float s = v.x + v.y + v.z + v.w;
    float ss = v.x * v.x + v.y * v.y + v.z * v.z + v.w * v.w;
    #pragma unroll
    for (int o = 1; o < 64; o <<= 1) { s += __shfl_xor(s, o); ss += __shfl_xor(ss, o); }
    float* red = smem;
    int w = t >> 6;
    if ((t & 63) == 0) { red[w] = s; red[4 + w] = ss; }
    __syncthreads();
    float S = red[0] + red[1] + red[2] + red[3];
    float SS = red[4] + red[5] + red[6] + red[7];
    float m = S * (1.0f / 1024.0f);
    float var = SS * (1.0f / 1024.0f) - m * m;
    float inv = rsqrtf(var + EPSF);
    float4 gv = ((const float4*)g)[t];
    float4 bv = ((const float4*)bta)[t];
    float4 o;
    o.x = (v.x - m) * inv * gv.x + bv.x;
    o.y = (v.y - m) * inv * gv.y + bv.y;
    o.z = (v.z - m) * inv * gv.z + bv.z;
    o.w = (v.w - m) * inv * gv.w + bv.w;
    ushort4 ob;
    ob.x = f2bf(o.x); ob.y = f2bf(o.y); ob.z = f2bf(o.z); ob.w = f2bf(o.w);
    ((ushort4*)(xn + (size_t)bs * 1024))[t] = ob;
    float4 wv = ((const float4*)w_dt)[t & 7];
    float part = o.x * wv.x + o.y * wv.y + o.z * wv.z + o.w * wv.w;
    part += __shfl_xor(part, 1);
    part += __shfl_xor(part, 2);
    part += __shfl_xor(part, 4);
    if ((t & 7) == 0) {
      int r = t >> 3;
      float z = part + b_dt[0];
      float sp = (z > 20.0f) ? z : log1pf(expf(z));
      log_a[(size_t)bs * 32 + r] = sp * (-expf(log_A[r]));
    }
  } else {
    int bid = blockIdx.x - 2048;
    bool isW1 = bid < 1024;
    const float* src; int R, C, r0, c0;
    if (isW1) { src = W1; R = 1024; C = 4096;
                c0 = (bid & 63) * 64; r0 = (bid >> 6) * 64; }
    else { bid -= 1024; src = W2; R = 4096; C = 1024;
           c0 = (bid & 15) * 64; r0 = (bid >> 4) * 64; }
    #pragma unroll
    for (int q = 0; q < 4; ++q) {
      int lin = q * 256 + tid;
      int r = lin >> 4, cq = lin & 15;
      float4 v = *(const float4*)(src + (size_t)(r0 + r) * C + c0 + cq * 4);
      smem[r * 65 + cq * 4 + 0] = v.x; smem[r * 65 + cq * 4 + 1] = v.y;
      smem[r * 65 + cq * 4 + 2] = v.z; smem[r * 65 + cq * 4 + 3] = v.w;
    }
    __syncthreads();
    #pragma unroll
    for (int q = 0; q < 4; ++q) {
      int lin = q * 256 + tid;
      int c = lin >> 4, rq = lin & 15;
      float f0 = smem[(rq * 4 + 0) * 65 + c];
      float f1 = smem[(rq * 4 + 1) * 65 + c];
      float f2 = smem[(rq * 4 + 2) * 65 + c];
      float f3 = smem[(rq * 4 + 3) * 65 + c];
      int n = c0 + c, k = r0 + rq * 4;
      int nt = n >> 4, l15n = n & 15;
      int kg = k >> 5, qd = (k >> 3) & 3, j0 = k & 7;
      if (isW1) {
        ushort4 o;
        o.x = f2bf(f0); o.y = f2bf(f1); o.z = f2bf(f2); o.w = f2bf(f3);
        *(ushort4*)(W1t + ((size_t)(nt * 32 + kg)) * 512 + qd * 128 + l15n * 8 + j0) = o;
      } else {
        int p = __builtin_amdgcn_cvt_pk_fp8_f32(f0 * 16.0f, f1 * 16.0f, 0, false);
        p = __builtin_amdgcn_cvt_pk_fp8_f32(f2 * 16.0f, f3 * 16.0f, p, true);
        *(int*)(W2t + ((size_t)(nt * 128 + kg)) * 512 + qd * 128 + l15n * 8 + j0) = p;
      }
    }
  }
}

// ---- chunked scan over bf16 xn (+ PASS1: out = ssm + bb2) ----
template <int PASS>
__global__ __launch_bounds__(256) void k_scan_pass(
    const unsigned short* __restrict__ xn, const float* __restrict__ x,
    const float* __restrict__ loga, float4* __restrict__ E, float* __restrict__ P,
    const float* __restrict__ bb2, float* __restrict__ out) {
  int bx = blockIdx.x;
  int b = bx >> 8, r = (bx >> 3) & 31, ch = bx & 7;
  int tid = threadIdx.x, cg = tid & 7, sub = tid >> 3;
  __shared__ float dec[128];
  __shared__ float4 sE[32][8];
  __shared__ float sP[32];
  if (tid < 128)
    dec[tid] = expf(loga[(size_t)(b * 1024 + ch * 128 + tid) * 32 + r]);
  __syncthreads();
  int t0 = ch * 128 + sub * 4;
  size_t base = ((size_t)(b * 1024 + t0) * 1024 + r * 32 + cg * 4) >> 2;  // 4-elem idx
  const ushort4* xn4 = (const ushort4*)xn;
  float4 xv[4];
  #pragma unroll
  for (int i = 0; i < 4; ++i) {
    ushort4 u = xn4[base + (size_t)i * 256];
    xv[i].x = bf2f(u.x); xv[i].y = bf2f(u.y); xv[i].z = bf2f(u.z); xv[i].w = bf2f(u.w);
  }
  float4 S = {0.f, 0.f, 0.f, 0.f};
  float Pl = 1.0f;
  #pragma unroll
  for (int i = 0; i < 4; ++i) {
    float d = dec[sub * 4 + i];
    S.x = d * S.x + xv[i].x; S.y = d * S.y + xv[i].y;
    S.z = d * S.z + xv[i].z; S.w = d * S.w + xv[i].w;
    Pl *= d;
  }
  sE[sub][cg] = S;
  if (cg == 0) sP[sub] = Pl;
  __syncthreads();
  if (PASS == 0) {
    if (tid < 8) {
      float4 Et = {0.f, 0.f, 0.f, 0.f};
      float PP = 1.0f;
      #pragma unroll
      for (int h = 0; h < 32; ++h) {
        float p = sP[h]; float4 e = sE[h][tid];
        Et.x = p * Et.x + e.x; Et.y = p * Et.y + e.y;
        Et.z = p * Et.z + e.z; Et.w = p * Et.w + e.w;
        PP *= p;
      }
      E[((size_t)(b * 32 + r) * 8 + ch) * 8 + tid] = Et;
      if (tid == 0) P[(b * 32 + r) * 8 + ch] = PP;
    }
  } else {
    float4 Sin = {0.f, 0.f, 0.f, 0.f};
    const float4* Eb = E + (size_t)(b * 32 + r) * 64 + cg;
    const float* Pb = P + (size_t)(b * 32 + r) * 8;
    for (int h = 0; h < ch; ++h) {
      float p = Pb[h]; float4 e = Eb[h * 8];
      Sin.x = p * Sin.x + e.x; Sin.y = p * Sin.y + e.y;
      Sin.z = p * Sin.z + e.z; Sin.w = p * Sin.w + e.w;
    }
    for (int h = 0; h < sub; ++h) {
      float p = sP[h]; float4 e = sE[h][cg];
      Sin.x = p * Sin.x + e.x; Sin.y = p * Sin.y + e.y;
      Sin.z = p * Sin.z + e.z; Sin.w = p * Sin.w + e.w;
    }
    float4 bb = ((const float4*)bb2)[r * 8 + cg];
    const float4* x4 = (const float4*)x;
    float4* out4 = (float4*)out;
    #pragma unroll
    for (int i = 0; i < 4; ++i) {
      float d = dec[sub * 4 + i];
      Sin.x = d * Sin.x + xv[i].x; Sin.y = d * Sin.y + xv[i].y;
      Sin.z = d * Sin.z + xv[i].z; Sin.w = d * Sin.w + xv[i].w;
      float4 rx = x4[base + (size_t)i * 256];
      float4 oi;
      oi.x = Sin.x + rx.x + bb.x; oi.y = Sin.y + rx.y + bb.y;
      oi.z = Sin.z + rx.z + bb.z; oi.w = Sin.w + rx.w + bb.w;
      out4[base + (size_t)i * 256] = oi;
    }
  }
}

// ---- LN2: reads out, subtracts bb2 -> fn (bf16, A-packed NKG=32) ----
__global__ __launch_bounds__(256) void k_ln2(
    const float* __restrict__ out, const float* __restrict__ bb2,
    const float* __restrict__ g, const float* __restrict__ bta,
    unsigned short* __restrict__ fn) {
  int bs = blockIdx.x;
  int t = threadIdx.x;
  float4 v = ((const float4*)(out + (size_t)bs * 1024))[t];
  float4 bb = ((const float4*)bb2)[t];
  v.x -= bb.x; v.y -= bb.y; v.z -= bb.z; v.w -= bb.w;
  float s = v.x + v.y + v.z + v.w;
  float ss = v.x * v.x + v.y * v.y + v.z * v.z + v.w * v.w;
  #pragma unroll
  for (int o = 1; o < 64; o <<= 1) { s += __shfl_xor(s, o); ss += __shfl_xor(ss, o); }
  __shared__ float red[8];
  int w = t >> 6;
  if ((t & 63) == 0) { red[w] = s; red[4 + w] = ss; }
  __syncthreads();
  float S = red[0] + red[1] + red[2] + red[3];
  float SS = red[4] + red[5] + red[6] + red[7];
  float m = S * (1.0f / 1024.0f);
  float var = SS * (1.0f / 1024.0f) - m * m;
  float inv = rsqrtf(var + EPSF);
  float4 gv = ((const float4*)g)[t];
  float4 bv = ((const float4*)bta)[t];
  ushort4 o;
  o.x = f2bf((v.x - m) * inv * gv.x + bv.x);
  o.y = f2bf((v.y - m) * inv * gv.y + bv.y);
  o.z = f2bf((v.z - m) * inv * gv.z + bv.z);
  o.w = f2bf((v.w - m) * inv * gv.w + bv.w);
  int mt = bs >> 4, l15m = bs & 15;
  int kg = t >> 3, qd = (t >> 1) & 3, j0 = (t & 1) * 4;
  *(ushort4*)(fn + ((size_t)(mt * 32 + kg)) * 512 + qd * 128 + l15m * 8 + j0) = o;
}

// ---- GEMM1 (bf16): packed direct-load, 4-stage pipeline, XCD decode.
// Epilogue: gelu(acc+bias) -> fp8 -> LDS repack -> coalesced hbf (A-packed NKG=128).
__global__ __launch_bounds__(256, 2) void k_gemm1(
    const unsigned short* __restrict__ Ap, const unsigned short* __restrict__ Bp,
    const float* __restrict__ bias, unsigned char* __restrict__ C8) {
  constexpr int NKG = 32, ITER = 32;
  __shared__ __align__(16) unsigned char sC[16384];
  int L = blockIdx.x;
  int xcd = L & 7;
  int nq = xcd & 3, mh = xcd >> 2;
  int rest = L >> 3;
  int nx = rest & 7, my = rest >> 3;
  int n0 = (nq * 8 + nx) * 128;
  int m0 = (mh * 8 + my) * 128;
  int tid = threadIdx.x;
  int wave = tid >> 6, lane = tid & 63;
  int wr = wave >> 1, wc = wave & 1;
  int l15 = lane & 15, quad = lane >> 4;
  int mt0 = (m0 >> 4) + wr * 4;
  int nt0 = (n0 >> 4) + wc * 4;
  const unsigned short* pa = Ap + ((size_t)mt0 * NKG) * 512 + lane * 8;
  const unsigned short* pb = Bp + ((size_t)nt0 * NKG) * 512 + lane * 8;

  f32x4 zero = {0.0f, 0.0f, 0.0f, 0.0f};
  f32x4 acc[4][4];
  #pragma unroll
  for (int i = 0; i < 4; ++i)
    #pragma unroll
    for (int j = 0; j < 4; ++j) acc[i][j] = zero;

  bf16x8 a[4][4], b[4][4];
  #pragma unroll
  for (int s = 0; s < 4; ++s)
    #pragma unroll
    for (int i = 0; i < 4; ++i) {
      a[s][i] = *(const bf16x8*)(pa + ((size_t)i * NKG + s) * 512);
      b[s][i] = *(const bf16x8*)(pb + ((size_t)i * NKG + s) * 512);
    }
  #pragma unroll 1
  for (int kg = 0; kg < ITER - 4; kg += 4) {
    #pragma unroll
    for (int s = 0; s < 4; ++s) {
      #pragma unroll
      for (int i = 0; i < 4; ++i)
        #pragma unroll
        for (int j = 0; j < 4; ++j)
          acc[i][j] = __builtin_amdgcn_mfma_f32_16x16x32_bf16(a[s][i], b[s][j], acc[i][j], 0, 0, 0);
      #pragma unroll
      for (int i = 0; i < 4; ++i) {
        a[s][i] = *(const bf16x8*)(pa + ((size_t)i * NKG + kg + 4 + s) * 512);
        b[s][i] = *(const bf16x8*)(pb + ((size_t)i * NKG + kg + 4 + s) * 512);
      }
    }
  }
  #pragma unroll
  for (int s = 0; s < 4; ++s)
    #pragma unroll
    for (int i = 0; i < 4; ++i)
      #pragma unroll
      for (int j = 0; j < 4; ++j)
        acc[i][j] = __builtin_amdgcn_mfma_f32_16x16x32_bf16(a[s][i], b[s][j], acc[i][j], 0, 0, 0);

  // epilogue: gelu -> fp8 into LDS (GEMM2 A-packed local tile), then coalesced dump
  #pragma unroll
  for (int i = 0; i < 4; ++i) {
    #pragma unroll
    for (int j = 0; j < 4; ++j) {
      int col_l = wc * 64 + j * 16 + l15;
      float bval = bias[n0 + col_l];
      int kg_l = col_l >> 5, q2 = (col_l >> 3) & 3, j2 = col_l & 7;
      unsigned char* ldst = sC + ((wr * 4 + i) * 4 + kg_l) * 512 + q2 * 128 + j2;
      float vv[4];
      #pragma unroll
      for (int v = 0; v < 4; ++v) {
        float val = acc[i][j][v] + bval;
        vv[v] = 0.5f * val * (1.0f + erff(val * 0.70710678118654752f));
      }
      int p01 = __builtin_amdgcn_cvt_pk_fp8_f32(vv[0], vv[1], 0, false);
      int p23 = __builtin_amdgcn_cvt_pk_fp8_f32(vv[2], vv[3], 0, false);
      ldst[(quad * 4 + 0) * 8] = (unsigned char)(p01 & 0xff);
      ldst[(quad * 4 + 1) * 8] = (unsigned char)((p01 >> 8) & 0xff);
      ldst[(quad * 4 + 2) * 8] = (unsigned char)(p23 & 0xff);
      ldst[(quad * 4 + 3) * 8] = (unsigned char)((p23 >> 8) & 0xff);
    }
  }
  __syncthreads();
  int mt2_0 = m0 >> 4, kg2_0 = n0 >> 5;
  #pragma unroll
  for (int p = 0; p < 2; ++p) {
    int idx = p * 256 + tid;
    int c = idx >> 4, inner = (idx & 15) * 32;
    *(int4*)(C8 + ((size_t)((mt2_0 + (c >> 2)) * 128 + kg2_0 + (c & 3))) * 512 + inner) =
        *(const int4*)(sC + c * 512 + inner);
    *(int4*)(C8 + ((size_t)((mt2_0 + (c >> 2)) * 128 + kg2_0 + (c & 3))) * 512 + inner + 16) =
        *(const int4*)(sC + c * 512 + inner + 16);
  }
}

// ---- GEMM2 (fp8 e4m3): packed direct-load, 8-stage pipeline, split-K=4,
// XCD decode; epilogue atomicAdd( acc * 1/16 ) into out (W2 was scaled x16).
__global__ __launch_bounds__(256, 2) void k_gemm2(
    const unsigned char* __restrict__ Ap, const unsigned char* __restrict__ Bp,
    float* __restrict__ O) {
  constexpr int NKG = 128, ITER = 32;
  int L = blockIdx.x;
  int xcd = L & 7;
  int ks = xcd >> 1, mh = xcd & 1;
  int rest = L >> 3;
  int nx = rest & 7, my = rest >> 3;
  int n0 = nx * 128;
  int m0 = (mh * 8 + my) * 128;
  int kg0 = ks * ITER;
  int tid = threadIdx.x;
  int wave = tid >> 6, lane = tid & 63;
  int wr = wave >> 1, wc = wave & 1;
  int l15 = lane & 15, quad = lane >> 4;
  int mt0 = (m0 >> 4) + wr * 4;
  int nt0 = (n0 >> 4) + wc * 4;
  const unsigned char* pa = Ap + ((size_t)mt0 * NKG + kg0) * 512 + lane * 8;
  const unsigned char* pb = Bp + ((size_t)nt0 * NKG + kg0) * 512 + lane * 8;

  f32x4 zero = {0.0f, 0.0f, 0.0f, 0.0f};
  f32x4 acc[4][4];
  #pragma unroll
  for (int i = 0; i < 4; ++i)
    #pragma unroll
    for (int j = 0; j < 4; ++j) acc[i][j] = zero;

  long a[8][4], b[8][4];
  #pragma unroll
  for (int s = 0; s < 8; ++s)
    #pragma unroll
    for (int i = 0; i < 4; ++i) {
      a[s][i] = *(const long*)(pa + ((size_t)i * NKG + s) * 512);
      b[s][i] = *(const long*)(pb + ((size_t)i * NKG + s) * 512);
    }
  #pragma unroll 1
  for (int kg = 0; kg < ITER - 8; kg += 8) {
    #pragma unroll
    for (int s = 0; s < 8; ++s) {
      #pragma unroll
      for (int i = 0; i < 4; ++i)
        #pragma unroll
        for (int j = 0; j < 4; ++j)
          acc[i][j] = __builtin_amdgcn_mfma_f32_16x16x32_fp8_fp8(a[s][i], b[s][j], acc[i][j], 0, 0, 0);
      #pragma unroll
      for (int i = 0; i < 4; ++i) {
        a[s][i] = *(const long*)(pa + ((size_t)i * NKG + kg + 8 + s) * 512);
        b[s][i] = *(const long*)(pb + ((size_t)i * NKG + kg + 8 + s) * 512);
      }
    }
  }
  #pragma unroll
  for (int s = 0; s < 8; ++s)
    #pragma unroll
    for (int i = 0; i < 4; ++i)
      #pragma unroll
      for (int j = 0; j < 4; ++j)
        acc[i][j] = __builtin_amdgcn_mfma_f32_16x16x32_fp8_fp8(a[s][i], b[s][j], acc[i][j], 0, 0, 0);

  #pragma unroll
  for (int i = 0; i < 4; ++i)
    #pragma unroll
    for (int j = 0; j < 4; ++j) {
      int col = n0 + wc * 64 + j * 16 + l15;
      #pragma unroll
      for (int v = 0; v < 4; ++v) {
        int row = m0 + wr * 64 + i * 16 + quad * 4 + v;
        atomicAdd(&O[(size_t)row * 1024 + col], acc[i][j][v] * 0.0625f);
      }
    }
}

extern "C" void kernel_launch(void* const* d_in, const int* in_sizes, int n_in,
                              void* d_out, int out_size, void* d_ws, size_t ws_size,
                              hipStream_t stream) {
  const float* x     = (const float*)d_in[0];
  const float* log_A = (const float*)d_in[1];
  const float* w_dt  = (const float*)d_in[2];
  const float* b_dt  = (const float*)d_in[3];
  const float* g_ssm = (const float*)d_in[4];
  const float* b_ssm = (const float*)d_in[5];
  const float* g_ffn = (const float*)d_in[6];
  const float* b_ffn = (const float*)d_in[7];
  const float* W1    = (const float*)d_in[8];
  const float* bb1   = (const float*)d_in[9];
  const float* W2    = (const float*)d_in[10];
  const float* bb2   = (const float*)d_in[11];
  float* out = (float*)d_out;

  const size_t MB = 1u << 20;
  char* ws = (char*)d_ws;
  unsigned short* xn   = (unsigned short*)(ws);              // 0-4 bf16
  unsigned short* W1t  = (unsigned short*)(ws + 4 * MB);     // 4-12 bf16 packed
  float* loga          = (float*)(ws + 12 * MB);             // 256 KB
  float4* Ebuf         = (float4*)(ws + 12 * MB + 262144);   // 64 KB
  float* Pbuf          = (float*)(ws + 12 * MB + 393216);    // 2 KB
  unsigned short* fn   = (unsigned short*)(ws + 13 * MB);    // 13-17 bf16 packed
  unsigned char* W2t   = (unsigned char*)(ws + 17 * MB);     // 17-21 fp8 packed
  unsigned char* hbf   = (unsigned char*)(ws + 21 * MB);     // 21-29 fp8 packed

  k_pre<<<4096, 256, 0, stream>>>(x, g_ssm, b_ssm, w_dt, b_dt, log_A, xn, loga,
                                  W1, W1t, W2, W2t);
  k_scan_pass<0><<<512, 256, 0, stream>>>(xn, x, loga, Ebuf, Pbuf, bb2, out);
  k_scan_pass<1><<<512, 256, 0, stream>>>(xn, x, loga, Ebuf, Pbuf, bb2, out);
  k_ln2<<<2048, 256, 0, stream>>>(out, bb2, g_ffn, b_ffn, fn);
  k_gemm1<<<512, 256, 0, stream>>>(fn, W1t, bb1, hbf);
  k_gemm2<<<512, 256, 0, stream>>>(hbf, W2t, out);
}

// Round 11
// 187.106 us; speedup vs baseline: 1.4647x; 1.0139x over previous
//
#include <hip/hip_runtime.h>
#include <math.h>

#define EPSF 1e-5f

typedef __attribute__((ext_vector_type(8))) __bf16 bf16x8;
typedef __attribute__((ext_vector_type(4))) float f32x4;

__device__ __forceinline__ unsigned short f2bf(float f) {
  unsigned int u = __float_as_uint(f);
  u += 0x7FFFu + ((u >> 16) & 1u);
  return (unsigned short)(u >> 16);
}
__device__ __forceinline__ float bf2f(unsigned short u) {
  return __uint_as_float((unsigned int)u << 16);
}

// Packed fragment-major fp8 layout (E=1 byte):
//   (row, k) -> ((row>>4)*NKG + (k>>5))*512 + ((k>>3)&3)*128 + (row&15)*8 + (k&7)
// A wave's 16x32 fragment = contiguous 512B block (lane*8B), fully coalesced.

// ---- fused: LN1+dt (0..2047) | W1 pack fp8x16 (2048..3071) | W2 pack fp8x16 (3072..4095)
__global__ __launch_bounds__(256) void k_pre(
    const float* __restrict__ x, const float* __restrict__ g, const float* __restrict__ bta,
    const float* __restrict__ w_dt, const float* __restrict__ b_dt,
    const float* __restrict__ log_A, unsigned short* __restrict__ xn, float* __restrict__ log_a,
    const float* __restrict__ W1, unsigned char* __restrict__ W1t,
    const float* __restrict__ W2, unsigned char* __restrict__ W2t) {
  __shared__ float smem[64 * 65];
  int tid = threadIdx.x;
  if (blockIdx.x < 2048) {
    int bs = blockIdx.x;
    int t = tid;
    float4 v = ((const float4*)(x + (size_t)bs * 1024))[t];
    float s = v.x + v.y + v.z + v.w;
    float ss = v.x * v.x + v.y * v.y + v.z * v.z + v.w * v.w;
    #pragma unroll
    for (int o = 1; o < 64; o <<= 1) { s += __shfl_xor(s, o); ss += __shfl_xor(ss, o); }
    float* red = smem;
    int w = t >> 6;
    if ((t & 63) == 0) { red[w] = s; red[4 + w] = ss; }
    __syncthreads();
    float S = red[0] + red[1] + red[2] + red[3];
    float SS = red[4] + red[5] + red[6] + red[7];
    float m = S * (1.0f / 1024.0f);
    float var = SS * (1.0f / 1024.0f) - m * m;
    float inv = rsqrtf(var + EPSF);
    float4 gv = ((const float4*)g)[t];
    float4 bv = ((const float4*)bta)[t];
    float4 o;
    o.x = (v.x - m) * inv * gv.x + bv.x;
    o.y = (v.y - m) * inv * gv.y + bv.y;
    o.z = (v.z - m) * inv * gv.z + bv.z;
    o.w = (v.w - m) * inv * gv.w + bv.w;
    ushort4 ob;
    ob.x = f2bf(o.x); ob.y = f2bf(o.y); ob.z = f2bf(o.z); ob.w = f2bf(o.w);
    ((ushort4*)(xn + (size_t)bs * 1024))[t] = ob;
    float4 wv = ((const float4*)w_dt)[t & 7];
    float part = o.x * wv.x + o.y * wv.y + o.z * wv.z + o.w * wv.w;
    part += __shfl_xor(part, 1);
    part += __shfl_xor(part, 2);
    part += __shfl_xor(part, 4);
    if ((t & 7) == 0) {
      int r = t >> 3;
      float z = part + b_dt[0];
      float sp = (z > 20.0f) ? z : log1pf(expf(z));
      log_a[(size_t)bs * 32 + r] = sp * (-expf(log_A[r]));
    }
  } else {
    int bid = blockIdx.x - 2048;
    bool isW1 = bid < 1024;
    const float* src; unsigned char* dst; int C, r0, c0, nkg;
    if (isW1) { src = W1; dst = W1t; C = 4096; nkg = 32;
                c0 = (bid & 63) * 64; r0 = (bid >> 6) * 64; }
    else { bid -= 1024; src = W2; dst = W2t; C = 1024; nkg = 128;
           c0 = (bid & 15) * 64; r0 = (bid >> 4) * 64; }
    #pragma unroll
    for (int q = 0; q < 4; ++q) {
      int lin = q * 256 + tid;
      int r = lin >> 4, cq = lin & 15;
      float4 v = *(const float4*)(src + (size_t)(r0 + r) * C + c0 + cq * 4);
      smem[r * 65 + cq * 4 + 0] = v.x; smem[r * 65 + cq * 4 + 1] = v.y;
      smem[r * 65 + cq * 4 + 2] = v.z; smem[r * 65 + cq * 4 + 3] = v.w;
    }
    __syncthreads();
    // coalesced pack: 512 items, each = 8 k-values for one n; 16-lane runs contiguous
    #pragma unroll
    for (int q = 0; q < 2; ++q) {
      int lin = q * 256 + tid;
      int c = lin & 63, rh = lin >> 6;          // rh in [0,8)
      int n = c0 + c, k = r0 + rh * 8;
      int nt = n >> 4, l15n = n & 15;
      int kg = k >> 5, qd = (k >> 3) & 3;
      int p0 = __builtin_amdgcn_cvt_pk_fp8_f32(
          smem[(rh * 8 + 0) * 65 + c] * 16.0f, smem[(rh * 8 + 1) * 65 + c] * 16.0f, 0, false);
      p0 = __builtin_amdgcn_cvt_pk_fp8_f32(
          smem[(rh * 8 + 2) * 65 + c] * 16.0f, smem[(rh * 8 + 3) * 65 + c] * 16.0f, p0, true);
      int p1 = __builtin_amdgcn_cvt_pk_fp8_f32(
          smem[(rh * 8 + 4) * 65 + c] * 16.0f, smem[(rh * 8 + 5) * 65 + c] * 16.0f, 0, false);
      p1 = __builtin_amdgcn_cvt_pk_fp8_f32(
          smem[(rh * 8 + 6) * 65 + c] * 16.0f, smem[(rh * 8 + 7) * 65 + c] * 16.0f, p1, true);
      int2 pk; pk.x = p0; pk.y = p1;
      *(int2*)(dst + ((size_t)(nt * nkg + kg)) * 512 + qd * 128 + l15n * 8) = pk;
    }
  }
}

// ---- chunked scan over bf16 xn (+ PASS1: out = ssm + bb2) ----
template <int PASS>
__global__ __launch_bounds__(256) void k_scan_pass(
    const unsigned short* __restrict__ xn, const float* __restrict__ x,
    const float* __restrict__ loga, float4* __restrict__ E, float* __restrict__ P,
    const float* __restrict__ bb2, float* __restrict__ out) {
  int bx = blockIdx.x;
  int b = bx >> 8, r = (bx >> 3) & 31, ch = bx & 7;
  int tid = threadIdx.x, cg = tid & 7, sub = tid >> 3;
  __shared__ float dec[128];
  __shared__ float4 sE[32][8];
  __shared__ float sP[32];
  if (tid < 128)
    dec[tid] = expf(loga[(size_t)(b * 1024 + ch * 128 + tid) * 32 + r]);
  __syncthreads();
  int t0 = ch * 128 + sub * 4;
  size_t base = ((size_t)(b * 1024 + t0) * 1024 + r * 32 + cg * 4) >> 2;
  const ushort4* xn4 = (const ushort4*)xn;
  float4 xv[4];
  #pragma unroll
  for (int i = 0; i < 4; ++i) {
    ushort4 u = xn4[base + (size_t)i * 256];
    xv[i].x = bf2f(u.x); xv[i].y = bf2f(u.y); xv[i].z = bf2f(u.z); xv[i].w = bf2f(u.w);
  }
  float4 S = {0.f, 0.f, 0.f, 0.f};
  float Pl = 1.0f;
  #pragma unroll
  for (int i = 0; i < 4; ++i) {
    float d = dec[sub * 4 + i];
    S.x = d * S.x + xv[i].x; S.y = d * S.y + xv[i].y;
    S.z = d * S.z + xv[i].z; S.w = d * S.w + xv[i].w;
    Pl *= d;
  }
  sE[sub][cg] = S;
  if (cg == 0) sP[sub] = Pl;
  __syncthreads();
  if (PASS == 0) {
    if (tid < 8) {
      float4 Et = {0.f, 0.f, 0.f, 0.f};
      float PP = 1.0f;
      #pragma unroll
      for (int h = 0; h < 32; ++h) {
        float p = sP[h]; float4 e = sE[h][tid];
        Et.x = p * Et.x + e.x; Et.y = p * Et.y + e.y;
        Et.z = p * Et.z + e.z; Et.w = p * Et.w + e.w;
        PP *= p;
      }
      E[((size_t)(b * 32 + r) * 8 + ch) * 8 + tid] = Et;
      if (tid == 0) P[(b * 32 + r) * 8 + ch] = PP;
    }
  } else {
    float4 Sin = {0.f, 0.f, 0.f, 0.f};
    const float4* Eb = E + (size_t)(b * 32 + r) * 64 + cg;
    const float* Pb = P + (size_t)(b * 32 + r) * 8;
    for (int h = 0; h < ch; ++h) {
      float p = Pb[h]; float4 e = Eb[h * 8];
      Sin.x = p * Sin.x + e.x; Sin.y = p * Sin.y + e.y;
      Sin.z = p * Sin.z + e.z; Sin.w = p * Sin.w + e.w;
    }
    for (int h = 0; h < sub; ++h) {
      float p = sP[h]; float4 e = sE[h][cg];
      Sin.x = p * Sin.x + e.x; Sin.y = p * Sin.y + e.y;
      Sin.z = p * Sin.z + e.z; Sin.w = p * Sin.w + e.w;
    }
    float4 bb = ((const float4*)bb2)[r * 8 + cg];
    const float4* x4 = (const float4*)x;
    float4* out4 = (float4*)out;
    #pragma unroll
    for (int i = 0; i < 4; ++i) {
      float d = dec[sub * 4 + i];
      Sin.x = d * Sin.x + xv[i].x; Sin.y = d * Sin.y + xv[i].y;
      Sin.z = d * Sin.z + xv[i].z; Sin.w = d * Sin.w + xv[i].w;
      float4 rx = x4[base + (size_t)i * 256];
      float4 oi;
      oi.x = Sin.x + rx.x + bb.x; oi.y = Sin.y + rx.y + bb.y;
      oi.z = Sin.z + rx.z + bb.z; oi.w = Sin.w + rx.w + bb.w;
      out4[base + (size_t)i * 256] = oi;
    }
  }
}

// ---- LN2: reads out, subtracts bb2 -> fn (fp8, A-packed NKG=32) ----
__global__ __launch_bounds__(256) void k_ln2(
    const float* __restrict__ out, const float* __restrict__ bb2,
    const float* __restrict__ g, const float* __restrict__ bta,
    unsigned char* __restrict__ fn) {
  int bs = blockIdx.x;
  int t = threadIdx.x;
  float4 v = ((const float4*)(out + (size_t)bs * 1024))[t];
  float4 bb = ((const float4*)bb2)[t];
  v.x -= bb.x; v.y -= bb.y; v.z -= bb.z; v.w -= bb.w;
  float s = v.x + v.y + v.z + v.w;
  float ss = v.x * v.x + v.y * v.y + v.z * v.z + v.w * v.w;
  #pragma unroll
  for (int o = 1; o < 64; o <<= 1) { s += __shfl_xor(s, o); ss += __shfl_xor(ss, o); }
  __shared__ float red[8];
  int w = t >> 6;
  if ((t & 63) == 0) { red[w] = s; red[4 + w] = ss; }
  __syncthreads();
  float S = red[0] + red[1] + red[2] + red[3];
  float SS = red[4] + red[5] + red[6] + red[7];
  float m = S * (1.0f / 1024.0f);
  float var = SS * (1.0f / 1024.0f) - m * m;
  float inv = rsqrtf(var + EPSF);
  float4 gv = ((const float4*)g)[t];
  float4 bv = ((const float4*)bta)[t];
  float f0 = (v.x - m) * inv * gv.x + bv.x;
  float f1 = (v.y - m) * inv * gv.y + bv.y;
  float f2 = (v.z - m) * inv * gv.z + bv.z;
  float f3 = (v.w - m) * inv * gv.w + bv.w;
  int p = __builtin_amdgcn_cvt_pk_fp8_f32(f0, f1, 0, false);
  p = __builtin_amdgcn_cvt_pk_fp8_f32(f2, f3, p, true);
  int mt = bs >> 4, l15m = bs & 15;
  int kg = t >> 3, qd = (t >> 1) & 3, j0 = (t & 1) * 4;
  *(int*)(fn + ((size_t)(mt * 32 + kg)) * 512 + qd * 128 + l15m * 8 + j0) = p;
}

// ---- GEMM1 (fp8 e4m3): packed direct-load, 8-stage pipeline, XCD decode.
// acc = 16*(fn@W1); epilogue gelu(acc/16+bias) -> fp8 -> LDS repack -> hbf (NKG=128).
__global__ __launch_bounds__(256, 2) void k_gemm1(
    const unsigned char* __restrict__ Ap, const unsigned char* __restrict__ Bp,
    const float* __restrict__ bias, unsigned char* __restrict__ C8) {
  constexpr int NKG = 32, ITER = 32;
  __shared__ __align__(16) unsigned char sC[16384];
  int L = blockIdx.x;
  int xcd = L & 7;
  int nq = xcd & 3, mh = xcd >> 2;
  int rest = L >> 3;
  int nx = rest & 7, my = rest >> 3;
  int n0 = (nq * 8 + nx) * 128;
  int m0 = (mh * 8 + my) * 128;
  int tid = threadIdx.x;
  int wave = tid >> 6, lane = tid & 63;
  int wr = wave >> 1, wc = wave & 1;
  int l15 = lane & 15, quad = lane >> 4;
  int mt0 = (m0 >> 4) + wr * 4;
  int nt0 = (n0 >> 4) + wc * 4;
  const unsigned char* pa = Ap + ((size_t)mt0 * NKG) * 512 + lane * 8;
  const unsigned char* pb = Bp + ((size_t)nt0 * NKG) * 512 + lane * 8;

  f32x4 zero = {0.0f, 0.0f, 0.0f, 0.0f};
  f32x4 acc[4][4];
  #pragma unroll
  for (int i = 0; i < 4; ++i)
    #pragma unroll
    for (int j = 0; j < 4; ++j) acc[i][j] = zero;

  long a[8][4], b[8][4];
  #pragma unroll
  for (int s = 0; s < 8; ++s)
    #pragma unroll
    for (int i = 0; i < 4; ++i) {
      a[s][i] = *(const long*)(pa + ((size_t)i * NKG + s) * 512);
      b[s][i] = *(const long*)(pb + ((size_t)i * NKG + s) * 512);
    }
  #pragma unroll 1
  for (int kg = 0; kg < ITER - 8; kg += 8) {
    #pragma unroll
    for (int s = 0; s < 8; ++s) {
      #pragma unroll
      for (int i = 0; i < 4; ++i)
        #pragma unroll
        for (int j = 0; j < 4; ++j)
          acc[i][j] = __builtin_amdgcn_mfma_f32_16x16x32_fp8_fp8(a[s][i], b[s][j], acc[i][j], 0, 0, 0);
      #pragma unroll
      for (int i = 0; i < 4; ++i) {
        a[s][i] = *(const long*)(pa + ((size_t)i * NKG + kg + 8 + s) * 512);
        b[s][i] = *(const long*)(pb + ((size_t)i * NKG + kg + 8 + s) * 512);
      }
    }
  }
  #pragma unroll
  for (int s = 0; s < 8; ++s)
    #pragma unroll
    for (int i = 0; i < 4; ++i)
      #pragma unroll
      for (int j = 0; j < 4; ++j)
        acc[i][j] = __builtin_amdgcn_mfma_f32_16x16x32_fp8_fp8(a[s][i], b[s][j], acc[i][j], 0, 0, 0);

  // epilogue: gelu(acc/16 + bias) -> fp8 into LDS (GEMM2 A-packed tile), coalesced dump
  #pragma unroll
  for (int i = 0; i < 4; ++i) {
    #pragma unroll
    for (int j = 0; j < 4; ++j) {
      int col_l = wc * 64 + j * 16 + l15;
      float bval = bias[n0 + col_l];
      int kg_l = col_l >> 5, q2 = (col_l >> 3) & 3, j2 = col_l & 7;
      unsigned char* ldst = sC + ((wr * 4 + i) * 4 + kg_l) * 512 + q2 * 128 + j2;
      float vv[4];
      #pragma unroll
      for (int v = 0; v < 4; ++v) {
        float val = acc[i][j][v] * 0.0625f + bval;
        vv[v] = 0.5f * val * (1.0f + erff(val * 0.70710678118654752f));
      }
      int p01 = __builtin_amdgcn_cvt_pk_fp8_f32(vv[0], vv[1], 0, false);
      int p23 = __builtin_amdgcn_cvt_pk_fp8_f32(vv[2], vv[3], 0, false);
      ldst[(quad * 4 + 0) * 8] = (unsigned char)(p01 & 0xff);
      ldst[(quad * 4 + 1) * 8] = (unsigned char)((p01 >> 8) & 0xff);
      ldst[(quad * 4 + 2) * 8] = (unsigned char)(p23 & 0xff);
      ldst[(quad * 4 + 3) * 8] = (unsigned char)((p23 >> 8) & 0xff);
    }
  }
  __syncthreads();
  int mt2_0 = m0 >> 4, kg2_0 = n0 >> 5;
  #pragma unroll
  for (int p = 0; p < 2; ++p) {
    int idx = p * 256 + tid;
    int c = idx >> 4, inner = (idx & 15) * 32;
    *(int4*)(C8 + ((size_t)((mt2_0 + (c >> 2)) * 128 + kg2_0 + (c & 3))) * 512 + inner) =
        *(const int4*)(sC + c * 512 + inner);
    *(int4*)(C8 + ((size_t)((mt2_0 + (c >> 2)) * 128 + kg2_0 + (c & 3))) * 512 + inner + 16) =
        *(const int4*)(sC + c * 512 + inner + 16);
  }
}

// ---- GEMM2 (fp8 e4m3): packed direct-load, 8-stage pipeline, split-K=4,
// XCD decode; epilogue atomicAdd( acc * 1/16 ) into out (W2 was scaled x16).
__global__ __launch_bounds__(256, 2) void k_gemm2(
    const unsigned char* __restrict__ Ap, const unsigned char* __restrict__ Bp,
    float* __restrict__ O) {
  constexpr int NKG = 128, ITER = 32;
  int L = blockIdx.x;
  int xcd = L & 7;
  int ks = xcd >> 1, mh = xcd & 1;
  int rest = L >> 3;
  int nx = rest & 7, my = rest >> 3;
  int n0 = nx * 128;
  int m0 = (mh * 8 + my) * 128;
  int kg0 = ks * ITER;
  int tid = threadIdx.x;
  int wave = tid >> 6, lane = tid & 63;
  int wr = wave >> 1, wc = wave & 1;
  int l15 = lane & 15, quad = lane >> 4;
  int mt0 = (m0 >> 4) + wr * 4;
  int nt0 = (n0 >> 4) + wc * 4;
  const unsigned char* pa = Ap + ((size_t)mt0 * NKG + kg0) * 512 + lane * 8;
  const unsigned char* pb = Bp + ((size_t)nt0 * NKG + kg0) * 512 + lane * 8;

  f32x4 zero = {0.0f, 0.0f, 0.0f, 0.0f};
  f32x4 acc[4][4];
  #pragma unroll
  for (int i = 0; i < 4; ++i)
    #pragma unroll
    for (int j = 0; j < 4; ++j) acc[i][j] = zero;

  long a[8][4], b[8][4];
  #pragma unroll
  for (int s = 0; s < 8; ++s)
    #pragma unroll
    for (int i = 0; i < 4; ++i) {
      a[s][i] = *(const long*)(pa + ((size_t)i * NKG + s) * 512);
      b[s][i] = *(const long*)(pb + ((size_t)i * NKG + s) * 512);
    }
  #pragma unroll 1
  for (int kg = 0; kg < ITER - 8; kg += 8) {
    #pragma unroll
    for (int s = 0; s < 8; ++s) {
      #pragma unroll
      for (int i = 0; i < 4; ++i)
        #pragma unroll
        for (int j = 0; j < 4; ++j)
          acc[i][j] = __builtin_amdgcn_mfma_f32_16x16x32_fp8_fp8(a[s][i], b[s][j], acc[i][j], 0, 0, 0);
      #pragma unroll
      for (int i = 0; i < 4; ++i) {
        a[s][i] = *(const long*)(pa + ((size_t)i * NKG + kg + 8 + s) * 512);
        b[s][i] = *(const long*)(pb + ((size_t)i * NKG + kg + 8 + s) * 512);
      }
    }
  }
  #pragma unroll
  for (int s = 0; s < 8; ++s)
    #pragma unroll
    for (int i = 0; i < 4; ++i)
      #pragma unroll
      for (int j = 0; j < 4; ++j)
        acc[i][j] = __builtin_amdgcn_mfma_f32_16x16x32_fp8_fp8(a[s][i], b[s][j], acc[i][j], 0, 0, 0);

  #pragma unroll
  for (int i = 0; i < 4; ++i)
    #pragma unroll
    for (int j = 0; j < 4; ++j) {
      int col = n0 + wc * 64 + j * 16 + l15;
      #pragma unroll
      for (int v = 0; v < 4; ++v) {
        int row = m0 + wr * 64 + i * 16 + quad * 4 + v;
        atomicAdd(&O[(size_t)row * 1024 + col], acc[i][j][v] * 0.0625f);
      }
    }
}

extern "C" void kernel_launch(void* const* d_in, const int* in_sizes, int n_in,
                              void* d_out, int out_size, void* d_ws, size_t ws_size,
                              hipStream_t stream) {
  const float* x     = (const float*)d_in[0];
  const float* log_A = (const float*)d_in[1];
  const float* w_dt  = (const float*)d_in[2];
  const float* b_dt  = (const float*)d_in[3];
  const float* g_ssm = (const float*)d_in[4];
  const float* b_ssm = (const float*)d_in[5];
  const float* g_ffn = (const float*)d_in[6];
  const float* b_ffn = (const float*)d_in[7];
  const float* W1    = (const float*)d_in[8];
  const float* bb1   = (const float*)d_in[9];
  const float* W2    = (const float*)d_in[10];
  const float* bb2   = (const float*)d_in[11];
  float* out = (float*)d_out;

  const size_t MB = 1u << 20;
  char* ws = (char*)d_ws;
  unsigned short* xn   = (unsigned short*)(ws);              // 0-4 bf16
  unsigned char* W1t   = (unsigned char*)(ws + 4 * MB);      // 4-8 fp8 packed
  float* loga          = (float*)(ws + 8 * MB);              // 256 KB
  float4* Ebuf         = (float4*)(ws + 8 * MB + 262144);    // 64 KB
  float* Pbuf          = (float*)(ws + 8 * MB + 393216);     // 2 KB
  unsigned char* fn    = (unsigned char*)(ws + 9 * MB);      // 9-11 fp8 packed
  unsigned char* W2t   = (unsigned char*)(ws + 11 * MB);     // 11-15 fp8 packed
  unsigned char* hbf   = (unsigned char*)(ws + 15 * MB);     // 15-23 fp8 packed

  k_pre<<<4096, 256, 0, stream>>>(x, g_ssm, b_ssm, w_dt, b_dt, log_A, xn, loga,
                                  W1, W1t, W2, W2t);
  k_scan_pass<0><<<512, 256, 0, stream>>>(xn, x, loga, Ebuf, Pbuf, bb2, out);
  k_scan_pass<1><<<512, 256, 0, stream>>>(xn, x, loga, Ebuf, Pbuf, bb2, out);
  k_ln2<<<2048, 256, 0, stream>>>(out, bb2, g_ffn, b_ffn, fn);
  k_gemm1<<<512, 256, 0, stream>>>(fn, W1t, bb1, hbf);
  k_gemm2<<<512, 256, 0, stream>>>(hbf, W2t, out);
}

// Round 12
// 174.585 us; speedup vs baseline: 1.5698x; 1.0717x over previous
//
#include <hip/hip_runtime.h>
#include <math.h>

#define EPSF 1e-5f

typedef __attribute__((ext_vector_type(4))) float f32x4;
typedef __attribute__((ext_vector_type(2))) long long2v;

__device__ __forceinline__ unsigned short f2bf(float f) {
  unsigned int u = __float_as_uint(f);
  u += 0x7FFFu + ((u >> 16) & 1u);
  return (unsigned short)(u >> 16);
}
__device__ __forceinline__ float bf2f(unsigned short u) {
  return __uint_as_float((unsigned int)u << 16);
}

// Pair-packed fragment-major fp8 layout: superblock = 16 rows x 64 k = 1024 B.
//   (row,k) -> ((row>>4)*NKGP + (k>>6))*1024 + (((k>>3)&3)*16 + (row&15))*16
//              + ((k>>5)&1)*8 + (k&7)
// Lane l (= ((k>>3)&3)*16 + row&15) loads 16 B: bytes 0-7 = kg even, 8-15 = kg odd.

// ---- fused: LN1+dt (0..2047) | W1 pack (2048..3071) | W2 pack (3072..4095) ----
__global__ __launch_bounds__(256) void k_pre(
    const float* __restrict__ x, const float* __restrict__ g, const float* __restrict__ bta,
    const float* __restrict__ w_dt, const float* __restrict__ b_dt,
    const float* __restrict__ log_A, unsigned short* __restrict__ xn, float* __restrict__ log_a,
    const float* __restrict__ W1, unsigned char* __restrict__ W1t,
    const float* __restrict__ W2, unsigned char* __restrict__ W2t) {
  __shared__ float smem[64 * 65];
  int tid = threadIdx.x;
  if (blockIdx.x < 2048) {
    int bs = blockIdx.x;
    int t = tid;
    float4 v = ((const float4*)(x + (size_t)bs * 1024))[t];
    float s = v.x + v.y + v.z + v.w;
    float ss = v.x * v.x + v.y * v.y + v.z * v.z + v.w * v.w;
    #pragma unroll
    for (int o = 1; o < 64; o <<= 1) { s += __shfl_xor(s, o); ss += __shfl_xor(ss, o); }
    float* red = smem;
    int w = t >> 6;
    if ((t & 63) == 0) { red[w] = s; red[4 + w] = ss; }
    __syncthreads();
    float S = red[0] + red[1] + red[2] + red[3];
    float SS = red[4] + red[5] + red[6] + red[7];
    float m = S * (1.0f / 1024.0f);
    float var = SS * (1.0f / 1024.0f) - m * m;
    float inv = rsqrtf(var + EPSF);
    float4 gv = ((const float4*)g)[t];
    float4 bv = ((const float4*)bta)[t];
    float4 o;
    o.x = (v.x - m) * inv * gv.x + bv.x;
    o.y = (v.y - m) * inv * gv.y + bv.y;
    o.z = (v.z - m) * inv * gv.z + bv.z;
    o.w = (v.w - m) * inv * gv.w + bv.w;
    ushort4 ob;
    ob.x = f2bf(o.x); ob.y = f2bf(o.y); ob.z = f2bf(o.z); ob.w = f2bf(o.w);
    ((ushort4*)(xn + (size_t)bs * 1024))[t] = ob;
    float4 wv = ((const float4*)w_dt)[t & 7];
    float part = o.x * wv.x + o.y * wv.y + o.z * wv.z + o.w * wv.w;
    part += __shfl_xor(part, 1);
    part += __shfl_xor(part, 2);
    part += __shfl_xor(part, 4);
    if ((t & 7) == 0) {
      int r = t >> 3;
      float z = part + b_dt[0];
      float sp = (z > 20.0f) ? z : log1pf(expf(z));
      log_a[(size_t)bs * 32 + r] = sp * (-expf(log_A[r]));
    }
  } else {
    int bid = blockIdx.x - 2048;
    bool isW1 = bid < 1024;
    const float* src; unsigned char* dst; int C, r0, c0, nkgp;
    if (isW1) { src = W1; dst = W1t; C = 4096; nkgp = 16;
                c0 = (bid & 63) * 64; r0 = (bid >> 6) * 64; }
    else { bid -= 1024; src = W2; dst = W2t; C = 1024; nkgp = 64;
           c0 = (bid & 15) * 64; r0 = (bid >> 4) * 64; }
    #pragma unroll
    for (int q = 0; q < 4; ++q) {
      int lin = q * 256 + tid;
      int r = lin >> 4, cq = lin & 15;
      float4 v = *(const float4*)(src + (size_t)(r0 + r) * C + c0 + cq * 4);
      smem[r * 65 + cq * 4 + 0] = v.x; smem[r * 65 + cq * 4 + 1] = v.y;
      smem[r * 65 + cq * 4 + 2] = v.z; smem[r * 65 + cq * 4 + 3] = v.w;
    }
    __syncthreads();
    #pragma unroll
    for (int q = 0; q < 2; ++q) {
      int lin = q * 256 + tid;
      int c = lin & 63, rh = lin >> 6;          // rh in [0,8): k-octet
      int n = c0 + c, k = r0 + rh * 8;
      int nt = n >> 4, l15n = n & 15;
      int kp = k >> 6, qd = (k >> 3) & 3, half = (k >> 5) & 1;
      int p0 = __builtin_amdgcn_cvt_pk_fp8_f32(
          smem[(rh * 8 + 0) * 65 + c] * 16.0f, smem[(rh * 8 + 1) * 65 + c] * 16.0f, 0, false);
      p0 = __builtin_amdgcn_cvt_pk_fp8_f32(
          smem[(rh * 8 + 2) * 65 + c] * 16.0f, smem[(rh * 8 + 3) * 65 + c] * 16.0f, p0, true);
      int p1 = __builtin_amdgcn_cvt_pk_fp8_f32(
          smem[(rh * 8 + 4) * 65 + c] * 16.0f, smem[(rh * 8 + 5) * 65 + c] * 16.0f, 0, false);
      p1 = __builtin_amdgcn_cvt_pk_fp8_f32(
          smem[(rh * 8 + 6) * 65 + c] * 16.0f, smem[(rh * 8 + 7) * 65 + c] * 16.0f, p1, true);
      int2 pk; pk.x = p0; pk.y = p1;
      *(int2*)(dst + ((size_t)(nt * nkgp + kp)) * 1024 + (qd * 16 + l15n) * 16 + half * 8) = pk;
    }
  }
}

// ---- chunked scan over bf16 xn (+ PASS1: out = ssm + bb2) ----
template <int PASS>
__global__ __launch_bounds__(256) void k_scan_pass(
    const unsigned short* __restrict__ xn, const float* __restrict__ x,
    const float* __restrict__ loga, float4* __restrict__ E, float* __restrict__ P,
    const float* __restrict__ bb2, float* __restrict__ out) {
  int bx = blockIdx.x;
  int b = bx >> 8, r = (bx >> 3) & 31, ch = bx & 7;
  int tid = threadIdx.x, cg = tid & 7, sub = tid >> 3;
  __shared__ float dec[128];
  __shared__ float4 sE[32][8];
  __shared__ float sP[32];
  if (tid < 128)
    dec[tid] = expf(loga[(size_t)(b * 1024 + ch * 128 + tid) * 32 + r]);
  __syncthreads();
  int t0 = ch * 128 + sub * 4;
  size_t base = ((size_t)(b * 1024 + t0) * 1024 + r * 32 + cg * 4) >> 2;
  const ushort4* xn4 = (const ushort4*)xn;
  float4 xv[4];
  #pragma unroll
  for (int i = 0; i < 4; ++i) {
    ushort4 u = xn4[base + (size_t)i * 256];
    xv[i].x = bf2f(u.x); xv[i].y = bf2f(u.y); xv[i].z = bf2f(u.z); xv[i].w = bf2f(u.w);
  }
  float4 S = {0.f, 0.f, 0.f, 0.f};
  float Pl = 1.0f;
  #pragma unroll
  for (int i = 0; i < 4; ++i) {
    float d = dec[sub * 4 + i];
    S.x = d * S.x + xv[i].x; S.y = d * S.y + xv[i].y;
    S.z = d * S.z + xv[i].z; S.w = d * S.w + xv[i].w;
    Pl *= d;
  }
  sE[sub][cg] = S;
  if (cg == 0) sP[sub] = Pl;
  __syncthreads();
  if (PASS == 0) {
    if (tid < 8) {
      float4 Et = {0.f, 0.f, 0.f, 0.f};
      float PP = 1.0f;
      #pragma unroll
      for (int h = 0; h < 32; ++h) {
        float p = sP[h]; float4 e = sE[h][tid];
        Et.x = p * Et.x + e.x; Et.y = p * Et.y + e.y;
        Et.z = p * Et.z + e.z; Et.w = p * Et.w + e.w;
        PP *= p;
      }
      E[((size_t)(b * 32 + r) * 8 + ch) * 8 + tid] = Et;
      if (tid == 0) P[(b * 32 + r) * 8 + ch] = PP;
    }
  } else {
    float4 Sin = {0.f, 0.f, 0.f, 0.f};
    const float4* Eb = E + (size_t)(b * 32 + r) * 64 + cg;
    const float* Pb = P + (size_t)(b * 32 + r) * 8;
    for (int h = 0; h < ch; ++h) {
      float p = Pb[h]; float4 e = Eb[h * 8];
      Sin.x = p * Sin.x + e.x; Sin.y = p * Sin.y + e.y;
      Sin.z = p * Sin.z + e.z; Sin.w = p * Sin.w + e.w;
    }
    for (int h = 0; h < sub; ++h) {
      float p = sP[h]; float4 e = sE[h][cg];
      Sin.x = p * Sin.x + e.x; Sin.y = p * Sin.y + e.y;
      Sin.z = p * Sin.z + e.z; Sin.w = p * Sin.w + e.w;
    }
    float4 bb = ((const float4*)bb2)[r * 8 + cg];
    const float4* x4 = (const float4*)x;
    float4* out4 = (float4*)out;
    #pragma unroll
    for (int i = 0; i < 4; ++i) {
      float d = dec[sub * 4 + i];
      Sin.x = d * Sin.x + xv[i].x; Sin.y = d * Sin.y + xv[i].y;
      Sin.z = d * Sin.z + xv[i].z; Sin.w = d * Sin.w + xv[i].w;
      float4 rx = x4[base + (size_t)i * 256];
      float4 oi;
      oi.x = Sin.x + rx.x + bb.x; oi.y = Sin.y + rx.y + bb.y;
      oi.z = Sin.z + rx.z + bb.z; oi.w = Sin.w + rx.w + bb.w;
      out4[base + (size_t)i * 256] = oi;
    }
  }
}

// ---- LN2: reads out, subtracts bb2 -> fn (fp8, pair-packed NKGP=16) ----
__global__ __launch_bounds__(256) void k_ln2(
    const float* __restrict__ out, const float* __restrict__ bb2,
    const float* __restrict__ g, const float* __restrict__ bta,
    unsigned char* __restrict__ fn) {
  int bs = blockIdx.x;
  int t = threadIdx.x;
  float4 v = ((const float4*)(out + (size_t)bs * 1024))[t];
  float4 bb = ((const float4*)bb2)[t];
  v.x -= bb.x; v.y -= bb.y; v.z -= bb.z; v.w -= bb.w;
  float s = v.x + v.y + v.z + v.w;
  float ss = v.x * v.x + v.y * v.y + v.z * v.z + v.w * v.w;
  #pragma unroll
  for (int o = 1; o < 64; o <<= 1) { s += __shfl_xor(s, o); ss += __shfl_xor(ss, o); }
  __shared__ float red[8];
  int w = t >> 6;
  if ((t & 63) == 0) { red[w] = s; red[4 + w] = ss; }
  __syncthreads();
  float S = red[0] + red[1] + red[2] + red[3];
  float SS = red[4] + red[5] + red[6] + red[7];
  float m = S * (1.0f / 1024.0f);
  float var = SS * (1.0f / 1024.0f) - m * m;
  float inv = rsqrtf(var + EPSF);
  float4 gv = ((const float4*)g)[t];
  float4 bv = ((const float4*)bta)[t];
  float f0 = (v.x - m) * inv * gv.x + bv.x;
  float f1 = (v.y - m) * inv * gv.y + bv.y;
  float f2 = (v.z - m) * inv * gv.z + bv.z;
  float f3 = (v.w - m) * inv * gv.w + bv.w;
  int p = __builtin_amdgcn_cvt_pk_fp8_f32(f0, f1, 0, false);
  p = __builtin_amdgcn_cvt_pk_fp8_f32(f2, f3, p, true);
  int mt = bs >> 4, l15m = bs & 15;
  int kp = t >> 4, qd = (t >> 1) & 3, half = (t >> 3) & 1, j0 = (t & 1) * 4;
  *(int*)(fn + ((size_t)(mt * 16 + kp)) * 1024 + (qd * 16 + l15m) * 16 + half * 8 + j0) = p;
}

// ---- GEMM1 (fp8): pair-packed direct-load (16B/lane = 2 kg), 4 pair-stages.
// acc = 16*(fn@W1); epilogue gelu(acc/16+bias) -> fp8 -> LDS -> hbf (pair-packed NKGP=64).
__global__ __launch_bounds__(256, 2) void k_gemm1(
    const unsigned char* __restrict__ Ap, const unsigned char* __restrict__ Bp,
    const float* __restrict__ bias, unsigned char* __restrict__ C8) {
  constexpr int NKGP = 16, ITERP = 16;
  __shared__ __align__(16) unsigned char sC[16384];
  int L = blockIdx.x;
  int xcd = L & 7;
  int nq = xcd & 3, mh = xcd >> 2;
  int rest = L >> 3;
  int nx = rest & 7, my = rest >> 3;
  int n0 = (nq * 8 + nx) * 128;
  int m0 = (mh * 8 + my) * 128;
  int tid = threadIdx.x;
  int wave = tid >> 6, lane = tid & 63;
  int wr = wave >> 1, wc = wave & 1;
  int l15 = lane & 15, quad = lane >> 4;
  int mt0 = (m0 >> 4) + wr * 4;
  int nt0 = (n0 >> 4) + wc * 4;
  const unsigned char* pa = Ap + (size_t)mt0 * NKGP * 1024 + lane * 16;
  const unsigned char* pb = Bp + (size_t)nt0 * NKGP * 1024 + lane * 16;

  f32x4 zero = {0.0f, 0.0f, 0.0f, 0.0f};
  f32x4 acc[4][4];
  #pragma unroll
  for (int i = 0; i < 4; ++i)
    #pragma unroll
    for (int j = 0; j < 4; ++j) acc[i][j] = zero;

  long2v a[4][4], b[4][4];
  #pragma unroll
  for (int s = 0; s < 4; ++s)
    #pragma unroll
    for (int i = 0; i < 4; ++i) {
      a[s][i] = *(const long2v*)(pa + ((size_t)i * NKGP + s) * 1024);
      b[s][i] = *(const long2v*)(pb + ((size_t)i * NKGP + s) * 1024);
    }
  #pragma unroll 1
  for (int kp = 0; kp < ITERP - 4; kp += 4) {
    #pragma unroll
    for (int s = 0; s < 4; ++s) {
      #pragma unroll
      for (int i = 0; i < 4; ++i)
        #pragma unroll
        for (int j = 0; j < 4; ++j)
          acc[i][j] = __builtin_amdgcn_mfma_f32_16x16x32_fp8_fp8(a[s][i].x, b[s][j].x, acc[i][j], 0, 0, 0);
      #pragma unroll
      for (int i = 0; i < 4; ++i)
        #pragma unroll
        for (int j = 0; j < 4; ++j)
          acc[i][j] = __builtin_amdgcn_mfma_f32_16x16x32_fp8_fp8(a[s][i].y, b[s][j].y, acc[i][j], 0, 0, 0);
      #pragma unroll
      for (int i = 0; i < 4; ++i) {
        a[s][i] = *(const long2v*)(pa + ((size_t)i * NKGP + kp + 4 + s) * 1024);
        b[s][i] = *(const long2v*)(pb + ((size_t)i * NKGP + kp + 4 + s) * 1024);
      }
    }
  }
  #pragma unroll
  for (int s = 0; s < 4; ++s) {
    #pragma unroll
    for (int i = 0; i < 4; ++i)
      #pragma unroll
      for (int j = 0; j < 4; ++j)
        acc[i][j] = __builtin_amdgcn_mfma_f32_16x16x32_fp8_fp8(a[s][i].x, b[s][j].x, acc[i][j], 0, 0, 0);
    #pragma unroll
    for (int i = 0; i < 4; ++i)
      #pragma unroll
      for (int j = 0; j < 4; ++j)
        acc[i][j] = __builtin_amdgcn_mfma_f32_16x16x32_fp8_fp8(a[s][i].y, b[s][j].y, acc[i][j], 0, 0, 0);
  }

  // epilogue: gelu(acc/16 + bias) -> fp8 into LDS (pair-packed local), coalesced dump
  #pragma unroll
  for (int i = 0; i < 4; ++i) {
    #pragma unroll
    for (int j = 0; j < 4; ++j) {
      int col_l = wc * 64 + j * 16 + l15;    // k_l of GEMM2, 0..127
      float bval = bias[n0 + col_l];
      int kp_l = col_l >> 6, q2 = (col_l >> 3) & 3, half2 = (col_l >> 5) & 1, j2 = col_l & 7;
      unsigned char* ldst = sC + ((wr * 4 + i) * 2 + kp_l) * 1024 + q2 * 256 + half2 * 8 + j2;
      float vv[4];
      #pragma unroll
      for (int v = 0; v < 4; ++v) {
        float val = acc[i][j][v] * 0.0625f + bval;
        vv[v] = 0.5f * val * (1.0f + erff(val * 0.70710678118654752f));
      }
      int p01 = __builtin_amdgcn_cvt_pk_fp8_f32(vv[0], vv[1], 0, false);
      int p23 = __builtin_amdgcn_cvt_pk_fp8_f32(vv[2], vv[3], 0, false);
      ldst[(quad * 4 + 0) * 16] = (unsigned char)(p01 & 0xff);
      ldst[(quad * 4 + 1) * 16] = (unsigned char)((p01 >> 8) & 0xff);
      ldst[(quad * 4 + 2) * 16] = (unsigned char)(p23 & 0xff);
      ldst[(quad * 4 + 3) * 16] = (unsigned char)((p23 >> 8) & 0xff);
    }
  }
  __syncthreads();
  int mt2_0 = m0 >> 4, kp2_0 = n0 >> 6;
  #pragma unroll
  for (int p = 0; p < 4; ++p) {
    int ci = p * 256 + tid;
    int sb = ci >> 6, off = (ci & 63) * 16;
    int mt2 = mt2_0 + (sb >> 1), kp2 = kp2_0 + (sb & 1);
    *(int4*)(C8 + ((size_t)(mt2 * 64 + kp2)) * 1024 + off) =
        *(const int4*)(sC + sb * 1024 + off);
  }
}

// ---- GEMM2 (fp8): pair-packed direct-load, 4 pair-stages, split-K=4, XCD decode;
// epilogue atomicAdd( acc * 1/16 ) into out (W2 scaled x16).
__global__ __launch_bounds__(256, 2) void k_gemm2(
    const unsigned char* __restrict__ Ap, const unsigned char* __restrict__ Bp,
    float* __restrict__ O) {
  constexpr int NKGP = 64, ITERP = 16;
  int L = blockIdx.x;
  int xcd = L & 7;
  int ks = xcd >> 1, mh = xcd & 1;
  int rest = L >> 3;
  int nx = rest & 7, my = rest >> 3;
  int n0 = nx * 128;
  int m0 = (mh * 8 + my) * 128;
  int kp0 = ks * ITERP;
  int tid = threadIdx.x;
  int wave = tid >> 6, lane = tid & 63;
  int wr = wave >> 1, wc = wave & 1;
  int l15 = lane & 15, quad = lane >> 4;
  int mt0 = (m0 >> 4) + wr * 4;
  int nt0 = (n0 >> 4) + wc * 4;
  const unsigned char* pa = Ap + ((size_t)mt0 * NKGP + kp0) * 1024 + lane * 16;
  const unsigned char* pb = Bp + ((size_t)nt0 * NKGP + kp0) * 1024 + lane * 16;

  f32x4 zero = {0.0f, 0.0f, 0.0f, 0.0f};
  f32x4 acc[4][4];
  #pragma unroll
  for (int i = 0; i < 4; ++i)
    #pragma unroll
    for (int j = 0; j < 4; ++j) acc[i][j] = zero;

  long2v a[4][4], b[4][4];
  #pragma unroll
  for (int s = 0; s < 4; ++s)
    #pragma unroll
    for (int i = 0; i < 4; ++i) {
      a[s][i] = *(const long2v*)(pa + ((size_t)i * NKGP + s) * 1024);
      b[s][i] = *(const long2v*)(pb + ((size_t)i * NKGP + s) * 1024);
    }
  #pragma unroll 1
  for (int kp = 0; kp < ITERP - 4; kp += 4) {
    #pragma unroll
    for (int s = 0; s < 4; ++s) {
      #pragma unroll
      for (int i = 0; i < 4; ++i)
        #pragma unroll
        for (int j = 0; j < 4; ++j)
          acc[i][j] = __builtin_amdgcn_mfma_f32_16x16x32_fp8_fp8(a[s][i].x, b[s][j].x, acc[i][j], 0, 0, 0);
      #pragma unroll
      for (int i = 0; i < 4; ++i)
        #pragma unroll
        for (int j = 0; j < 4; ++j)
          acc[i][j] = __builtin_amdgcn_mfma_f32_16x16x32_fp8_fp8(a[s][i].y, b[s][j].y, acc[i][j], 0, 0, 0);
      #pragma unroll
      for (int i = 0; i < 4; ++i) {
        a[s][i] = *(const long2v*)(pa + ((size_t)i * NKGP + kp + 4 + s) * 1024);
        b[s][i] = *(const long2v*)(pb + ((size_t)i * NKGP + kp + 4 + s) * 1024);
      }
    }
  }
  #pragma unroll
  for (int s = 0; s < 4; ++s) {
    #pragma unroll
    for (int i = 0; i < 4; ++i)
      #pragma unroll
      for (int j = 0; j < 4; ++j)
        acc[i][j] = __builtin_amdgcn_mfma_f32_16x16x32_fp8_fp8(a[s][i].x, b[s][j].x, acc[i][j], 0, 0, 0);
    #pragma unroll
    for (int i = 0; i < 4; ++i)
      #pragma unroll
      for (int j = 0; j < 4; ++j)
        acc[i][j] = __builtin_amdgcn_mfma_f32_16x16x32_fp8_fp8(a[s][i].y, b[s][j].y, acc[i][j], 0, 0, 0);
  }

  #pragma unroll
  for (int i = 0; i < 4; ++i)
    #pragma unroll
    for (int j = 0; j < 4; ++j) {
      int col = n0 + wc * 64 + j * 16 + l15;
      #pragma unroll
      for (int v = 0; v < 4; ++v) {
        int row = m0 + wr * 64 + i * 16 + quad * 4 + v;
        atomicAdd(&O[(size_t)row * 1024 + col], acc[i][j][v] * 0.0625f);
      }
    }
}

extern "C" void kernel_launch(void* const* d_in, const int* in_sizes, int n_in,
                              void* d_out, int out_size, void* d_ws, size_t ws_size,
                              hipStream_t stream) {
  const float* x     = (const float*)d_in[0];
  const float* log_A = (const float*)d_in[1];
  const float* w_dt  = (const float*)d_in[2];
  const float* b_dt  = (const float*)d_in[3];
  const float* g_ssm = (const float*)d_in[4];
  const float* b_ssm = (const float*)d_in[5];
  const float* g_ffn = (const float*)d_in[6];
  const float* b_ffn = (const float*)d_in[7];
  const float* W1    = (const float*)d_in[8];
  const float* bb1   = (const float*)d_in[9];
  const float* W2    = (const float*)d_in[10];
  const float* bb2   = (const float*)d_in[11];
  float* out = (float*)d_out;

  const size_t MB = 1u << 20;
  char* ws = (char*)d_ws;
  unsigned short* xn   = (unsigned short*)(ws);              // 0-4 bf16
  unsigned char* W1t   = (unsigned char*)(ws + 4 * MB);      // 4-8 fp8 pair-packed
  float* loga          = (float*)(ws + 8 * MB);              // 256 KB
  float4* Ebuf         = (float4*)(ws + 8 * MB + 262144);    // 64 KB
  float* Pbuf          = (float*)(ws + 8 * MB + 393216);     // 2 KB
  unsigned char* fn    = (unsigned char*)(ws + 9 * MB);      // 9-11 fp8 pair-packed
  unsigned char* W2t   = (unsigned char*)(ws + 11 * MB);     // 11-15 fp8 pair-packed
  unsigned char* hbf   = (unsigned char*)(ws + 15 * MB);     // 15-23 fp8 pair-packed

  k_pre<<<4096, 256, 0, stream>>>(x, g_ssm, b_ssm, w_dt, b_dt, log_A, xn, loga,
                                  W1, W1t, W2, W2t);
  k_scan_pass<0><<<512, 256, 0, stream>>>(xn, x, loga, Ebuf, Pbuf, bb2, out);
  k_scan_pass<1><<<512, 256, 0, stream>>>(xn, x, loga, Ebuf, Pbuf, bb2, out);
  k_ln2<<<2048, 256, 0, stream>>>(out, bb2, g_ffn, b_ffn, fn);
  k_gemm1<<<512, 256, 0, stream>>>(fn, W1t, bb1, hbf);
  k_gemm2<<<512, 256, 0, stream>>>(hbf, W2t, out);
}

// Round 13
// 173.909 us; speedup vs baseline: 1.5759x; 1.0039x over previous
//
#include <hip/hip_runtime.h>
#include <math.h>

#define EPSF 1e-5f

typedef __attribute__((ext_vector_type(4))) float f32x4;
typedef __attribute__((ext_vector_type(2))) long long2v;

__device__ __forceinline__ unsigned short f2bf(float f) {
  unsigned int u = __float_as_uint(f);
  u += 0x7FFFu + ((u >> 16) & 1u);
  return (unsigned short)(u >> 16);
}
__device__ __forceinline__ float bf2f(unsigned short u) {
  return __uint_as_float((unsigned int)u << 16);
}

__device__ __forceinline__ void async_load16(const void* g, void* l) {
  __builtin_amdgcn_global_load_lds(
      (const __attribute__((address_space(1))) void*)g,
      (__attribute__((address_space(3))) void*)l, 16, 0, 0);
}

// Pair-packed fragment-major fp8 layout: superblock = 16 rows x 64 k = 1024 B.
//   (row,k) -> ((row>>4)*NKGP + (k>>6))*1024 + (((k>>3)&3)*16 + (row&15))*16
//              + ((k>>5)&1)*8 + (k&7)
// Lane l loads 16 B: bytes 0-7 = kg even, 8-15 = kg odd. A superblock is exactly
// one wave-wide global_load_lds (uniform base + lane*16).

// ---- fused: LN1+dt (0..2047) | W1 pack (2048..3071) | W2 pack (3072..4095) ----
__global__ __launch_bounds__(256) void k_pre(
    const float* __restrict__ x, const float* __restrict__ g, const float* __restrict__ bta,
    const float* __restrict__ w_dt, const float* __restrict__ b_dt,
    const float* __restrict__ log_A, unsigned short* __restrict__ xn, float* __restrict__ log_a,
    const float* __restrict__ W1, unsigned char* __restrict__ W1t,
    const float* __restrict__ W2, unsigned char* __restrict__ W2t) {
  __shared__ float smem[64 * 65];
  int tid = threadIdx.x;
  if (blockIdx.x < 2048) {
    int bs = blockIdx.x;
    int t = tid;
    float4 v = ((const float4*)(x + (size_t)bs * 1024))[t];
    float s = v.x + v.y + v.z + v.w;
    float ss = v.x * v.x + v.y * v.y + v.z * v.z + v.w * v.w;
    #pragma unroll
    for (int o = 1; o < 64; o <<= 1) { s += __shfl_xor(s, o); ss += __shfl_xor(ss, o); }
    float* red = smem;
    int w = t >> 6;
    if ((t & 63) == 0) { red[w] = s; red[4 + w] = ss; }
    __syncthreads();
    float S = red[0] + red[1] + red[2] + red[3];
    float SS = red[4] + red[5] + red[6] + red[7];
    float m = S * (1.0f / 1024.0f);
    float var = SS * (1.0f / 1024.0f) - m * m;
    float inv = rsqrtf(var + EPSF);
    float4 gv = ((const float4*)g)[t];
    float4 bv = ((const float4*)bta)[t];
    float4 o;
    o.x = (v.x - m) * inv * gv.x + bv.x;
    o.y = (v.y - m) * inv * gv.y + bv.y;
    o.z = (v.z - m) * inv * gv.z + bv.z;
    o.w = (v.w - m) * inv * gv.w + bv.w;
    ushort4 ob;
    ob.x = f2bf(o.x); ob.y = f2bf(o.y); ob.z = f2bf(o.z); ob.w = f2bf(o.w);
    ((ushort4*)(xn + (size_t)bs * 1024))[t] = ob;
    float4 wv = ((const float4*)w_dt)[t & 7];
    float part = o.x * wv.x + o.y * wv.y + o.z * wv.z + o.w * wv.w;
    part += __shfl_xor(part, 1);
    part += __shfl_xor(part, 2);
    part += __shfl_xor(part, 4);
    if ((t & 7) == 0) {
      int r = t >> 3;
      float z = part + b_dt[0];
      float sp = (z > 20.0f) ? z : log1pf(expf(z));
      log_a[(size_t)bs * 32 + r] = sp * (-expf(log_A[r]));
    }
  } else {
    int bid = blockIdx.x - 2048;
    bool isW1 = bid < 1024;
    const float* src; unsigned char* dst; int C, r0, c0, nkgp;
    if (isW1) { src = W1; dst = W1t; C = 4096; nkgp = 16;
                c0 = (bid & 63) * 64; r0 = (bid >> 6) * 64; }
    else { bid -= 1024; src = W2; dst = W2t; C = 1024; nkgp = 64;
           c0 = (bid & 15) * 64; r0 = (bid >> 4) * 64; }
    #pragma unroll
    for (int q = 0; q < 4; ++q) {
      int lin = q * 256 + tid;
      int r = lin >> 4, cq = lin & 15;
      float4 v = *(const float4*)(src + (size_t)(r0 + r) * C + c0 + cq * 4);
      smem[r * 65 + cq * 4 + 0] = v.x; smem[r * 65 + cq * 4 + 1] = v.y;
      smem[r * 65 + cq * 4 + 2] = v.z; smem[r * 65 + cq * 4 + 3] = v.w;
    }
    __syncthreads();
    #pragma unroll
    for (int q = 0; q < 2; ++q) {
      int lin = q * 256 + tid;
      int c = lin & 63, rh = lin >> 6;          // rh in [0,8): k-octet
      int n = c0 + c, k = r0 + rh * 8;
      int nt = n >> 4, l15n = n & 15;
      int kp = k >> 6, qd = (k >> 3) & 3, half = (k >> 5) & 1;
      int p0 = __builtin_amdgcn_cvt_pk_fp8_f32(
          smem[(rh * 8 + 0) * 65 + c] * 16.0f, smem[(rh * 8 + 1) * 65 + c] * 16.0f, 0, false);
      p0 = __builtin_amdgcn_cvt_pk_fp8_f32(
          smem[(rh * 8 + 2) * 65 + c] * 16.0f, smem[(rh * 8 + 3) * 65 + c] * 16.0f, p0, true);
      int p1 = __builtin_amdgcn_cvt_pk_fp8_f32(
          smem[(rh * 8 + 4) * 65 + c] * 16.0f, smem[(rh * 8 + 5) * 65 + c] * 16.0f, 0, false);
      p1 = __builtin_amdgcn_cvt_pk_fp8_f32(
          smem[(rh * 8 + 6) * 65 + c] * 16.0f, smem[(rh * 8 + 7) * 65 + c] * 16.0f, p1, true);
      int2 pk; pk.x = p0; pk.y = p1;
      *(int2*)(dst + ((size_t)(nt * nkgp + kp)) * 1024 + (qd * 16 + l15n) * 16 + half * 8) = pk;
    }
  }
}

// ---- chunked scan over bf16 xn (+ PASS1: out = ssm + bb2) ----
template <int PASS>
__global__ __launch_bounds__(256) void k_scan_pass(
    const unsigned short* __restrict__ xn, const float* __restrict__ x,
    const float* __restrict__ loga, float4* __restrict__ E, float* __restrict__ P,
    const float* __restrict__ bb2, float* __restrict__ out) {
  int bx = blockIdx.x;
  int b = bx >> 8, r = (bx >> 3) & 31, ch = bx & 7;
  int tid = threadIdx.x, cg = tid & 7, sub = tid >> 3;
  __shared__ float dec[128];
  __shared__ float4 sE[32][8];
  __shared__ float sP[32];
  if (tid < 128)
    dec[tid] = expf(loga[(size_t)(b * 1024 + ch * 128 + tid) * 32 + r]);
  __syncthreads();
  int t0 = ch * 128 + sub * 4;
  size_t base = ((size_t)(b * 1024 + t0) * 1024 + r * 32 + cg * 4) >> 2;
  const ushort4* xn4 = (const ushort4*)xn;
  float4 xv[4];
  #pragma unroll
  for (int i = 0; i < 4; ++i) {
    ushort4 u = xn4[base + (size_t)i * 256];
    xv[i].x = bf2f(u.x); xv[i].y = bf2f(u.y); xv[i].z = bf2f(u.z); xv[i].w = bf2f(u.w);
  }
  float4 S = {0.f, 0.f, 0.f, 0.f};
  float Pl = 1.0f;
  #pragma unroll
  for (int i = 0; i < 4; ++i) {
    float d = dec[sub * 4 + i];
    S.x = d * S.x + xv[i].x; S.y = d * S.y + xv[i].y;
    S.z = d * S.z + xv[i].z; S.w = d * S.w + xv[i].w;
    Pl *= d;
  }
  sE[sub][cg] = S;
  if (cg == 0) sP[sub] = Pl;
  __syncthreads();
  if (PASS == 0) {
    if (tid < 8) {
      float4 Et = {0.f, 0.f, 0.f, 0.f};
      float PP = 1.0f;
      #pragma unroll
      for (int h = 0; h < 32; ++h) {
        float p = sP[h]; float4 e = sE[h][tid];
        Et.x = p * Et.x + e.x; Et.y = p * Et.y + e.y;
        Et.z = p * Et.z + e.z; Et.w = p * Et.w + e.w;
        PP *= p;
      }
      E[((size_t)(b * 32 + r) * 8 + ch) * 8 + tid] = Et;
      if (tid == 0) P[(b * 32 + r) * 8 + ch] = PP;
    }
  } else {
    float4 Sin = {0.f, 0.f, 0.f, 0.f};
    const float4* Eb = E + (size_t)(b * 32 + r) * 64 + cg;
    const float* Pb = P + (size_t)(b * 32 + r) * 8;
    for (int h = 0; h < ch; ++h) {
      float p = Pb[h]; float4 e = Eb[h * 8];
      Sin.x = p * Sin.x + e.x; Sin.y = p * Sin.y + e.y;
      Sin.z = p * Sin.z + e.z; Sin.w = p * Sin.w + e.w;
    }
    for (int h = 0; h < sub; ++h) {
      float p = sP[h]; float4 e = sE[h][cg];
      Sin.x = p * Sin.x + e.x; Sin.y = p * Sin.y + e.y;
      Sin.z = p * Sin.z + e.z; Sin.w = p * Sin.w + e.w;
    }
    float4 bb = ((const float4*)bb2)[r * 8 + cg];
    const float4* x4 = (const float4*)x;
    float4* out4 = (float4*)out;
    #pragma unroll
    for (int i = 0; i < 4; ++i) {
      float d = dec[sub * 4 + i];
      Sin.x = d * Sin.x + xv[i].x; Sin.y = d * Sin.y + xv[i].y;
      Sin.z = d * Sin.z + xv[i].z; Sin.w = d * Sin.w + xv[i].w;
      float4 rx = x4[base + (size_t)i * 256];
      float4 oi;
      oi.x = Sin.x + rx.x + bb.x; oi.y = Sin.y + rx.y + bb.y;
      oi.z = Sin.z + rx.z + bb.z; oi.w = Sin.w + rx.w + bb.w;
      out4[base + (size_t)i * 256] = oi;
    }
  }
}

// ---- LN2: reads out, subtracts bb2 -> fn (fp8, pair-packed NKGP=16) ----
__global__ __launch_bounds__(256) void k_ln2(
    const float* __restrict__ out, const float* __restrict__ bb2,
    const float* __restrict__ g, const float* __restrict__ bta,
    unsigned char* __restrict__ fn) {
  int bs = blockIdx.x;
  int t = threadIdx.x;
  float4 v = ((const float4*)(out + (size_t)bs * 1024))[t];
  float4 bb = ((const float4*)bb2)[t];
  v.x -= bb.x; v.y -= bb.y; v.z -= bb.z; v.w -= bb.w;
  float s = v.x + v.y + v.z + v.w;
  float ss = v.x * v.x + v.y * v.y + v.z * v.z + v.w * v.w;
  #pragma unroll
  for (int o = 1; o < 64; o <<= 1) { s += __shfl_xor(s, o); ss += __shfl_xor(ss, o); }
  __shared__ float red[8];
  int w = t >> 6;
  if ((t & 63) == 0) { red[w] = s; red[4 + w] = ss; }
  __syncthreads();
  float S = red[0] + red[1] + red[2] + red[3];
  float SS = red[4] + red[5] + red[6] + red[7];
  float m = S * (1.0f / 1024.0f);
  float var = SS * (1.0f / 1024.0f) - m * m;
  float inv = rsqrtf(var + EPSF);
  float4 gv = ((const float4*)g)[t];
  float4 bv = ((const float4*)bta)[t];
  float f0 = (v.x - m) * inv * gv.x + bv.x;
  float f1 = (v.y - m) * inv * gv.y + bv.y;
  float f2 = (v.z - m) * inv * gv.z + bv.z;
  float f3 = (v.w - m) * inv * gv.w + bv.w;
  int p = __builtin_amdgcn_cvt_pk_fp8_f32(f0, f1, 0, false);
  p = __builtin_amdgcn_cvt_pk_fp8_f32(f2, f3, p, true);
  int mt = bs >> 4, l15m = bs & 15;
  int kp = t >> 4, qd = (t >> 1) & 3, half = (t >> 3) & 1, j0 = (t & 1) * 4;
  *(int*)(fn + ((size_t)(mt * 16 + kp)) * 1024 + (qd * 16 + l15m) * 16 + half * 8 + j0) = p;
}

// ---- LDS-staged fp8 GEMM core: 128x128 block, BK=256 (4 kp/stage), 4 stages,
// single 64KB LDS buffer, global_load_lds 16B (waves 0-1: A, 2-3: B), one
// barrier pair per stage. Fragments via conflict-free ds_read_b128.
// EPI 0 (GEMM1): gelu(acc/16+bias) -> fp8 -> LDS repack -> C8 (pair-packed NKGP=64)
// EPI 1 (GEMM2): atomicAdd(acc/16) into fp32 O (split-K=4 over blockIdx ks bits)
template <int EPI, int NKGP>
__global__ __launch_bounds__(256, 2) void k_gemm_lds(
    const unsigned char* __restrict__ Ap, const unsigned char* __restrict__ Bp,
    const float* __restrict__ bias, void* __restrict__ C) {
  __shared__ __align__(16) unsigned char sAB[65536];
  unsigned char* sA = sAB;
  unsigned char* sB = sAB + 32768;
  int L = blockIdx.x;
  int m0, n0, kp0;
  if (EPI == 0) {
    int xcd = L & 7;
    int nq = xcd & 3, mh = xcd >> 2;
    int rest = L >> 3;
    int nx = rest & 7, my = rest >> 3;
    n0 = (nq * 8 + nx) * 128;
    m0 = (mh * 8 + my) * 128;
    kp0 = 0;
  } else {
    int xcd = L & 7;
    int ks = xcd >> 1, mh = xcd & 1;
    int rest = L >> 3;
    int nx = rest & 7, my = rest >> 3;
    n0 = nx * 128;
    m0 = (mh * 8 + my) * 128;
    kp0 = ks * 16;
  }
  int tid = threadIdx.x;
  int wave = tid >> 6, lane = tid & 63;
  int wr = wave >> 1, wc = wave & 1;
  int l15 = lane & 15, quad = lane >> 4;
  int mt0b = m0 >> 4, nt0b = n0 >> 4;

  f32x4 zero = {0.0f, 0.0f, 0.0f, 0.0f};
  f32x4 acc[4][4];
  #pragma unroll
  for (int i = 0; i < 4; ++i)
    #pragma unroll
    for (int j = 0; j < 4; ++j) acc[i][j] = zero;

  // staging pointers: waves 0-1 stage A (32 superblocks), waves 2-3 stage B
  const unsigned char* gsrc = (wave < 2) ? Ap : Bp;
  int rt0 = (wave < 2) ? mt0b : nt0b;
  unsigned char* ldst = ((wave < 2) ? sA : sB) + (wave & 1) * 16384;
  int sb0 = (wave & 1) * 16;  // first superblock index this wave handles

  #pragma unroll 1
  for (int st = 0; st < 4; ++st) {
    int kps = kp0 + st * 4;
    #pragma unroll
    for (int t = 0; t < 16; ++t) {
      int sb = sb0 + t;
      int rt = sb >> 2, kl = sb & 3;
      async_load16(gsrc + ((size_t)(rt0 + rt) * NKGP + kps + kl) * 1024 + lane * 16,
                   ldst + t * 1024);
    }
    __syncthreads();
    #pragma unroll
    for (int kl = 0; kl < 4; ++kl) {
      long2v af[4], bf[4];
      #pragma unroll
      for (int i = 0; i < 4; ++i)
        af[i] = *(const long2v*)(sA + ((wr * 4 + i) * 4 + kl) * 1024 + lane * 16);
      #pragma unroll
      for (int j = 0; j < 4; ++j)
        bf[j] = *(const long2v*)(sB + ((wc * 4 + j) * 4 + kl) * 1024 + lane * 16);
      #pragma unroll
      for (int i = 0; i < 4; ++i)
        #pragma unroll
        for (int j = 0; j < 4; ++j)
          acc[i][j] = __builtin_amdgcn_mfma_f32_16x16x32_fp8_fp8(af[i].x, bf[j].x, acc[i][j], 0, 0, 0);
      #pragma unroll
      for (int i = 0; i < 4; ++i)
        #pragma unroll
        for (int j = 0; j < 4; ++j)
          acc[i][j] = __builtin_amdgcn_mfma_f32_16x16x32_fp8_fp8(af[i].y, bf[j].y, acc[i][j], 0, 0, 0);
    }
    __syncthreads();
  }

  if (EPI == 0) {
    // epilogue: gelu(acc/16 + bias) -> fp8 into LDS (pair-packed local), coalesced dump
    unsigned char* sC = sAB;   // reuse (16 KB needed; all compute done)
    #pragma unroll
    for (int i = 0; i < 4; ++i) {
      #pragma unroll
      for (int j = 0; j < 4; ++j) {
        int col_l = wc * 64 + j * 16 + l15;    // k_l of GEMM2, 0..127
        float bval = bias[n0 + col_l];
        int kp_l = col_l >> 6, q2 = (col_l >> 3) & 3, half2 = (col_l >> 5) & 1, j2 = col_l & 7;
        unsigned char* ld = sC + ((wr * 4 + i) * 2 + kp_l) * 1024 + q2 * 256 + half2 * 8 + j2;
        float vv[4];
        #pragma unroll
        for (int v = 0; v < 4; ++v) {
          float val = acc[i][j][v] * 0.0625f + bval;
          vv[v] = 0.5f * val * (1.0f + erff(val * 0.70710678118654752f));
        }
        int p01 = __builtin_amdgcn_cvt_pk_fp8_f32(vv[0], vv[1], 0, false);
        int p23 = __builtin_amdgcn_cvt_pk_fp8_f32(vv[2], vv[3], 0, false);
        ld[(quad * 4 + 0) * 16] = (unsigned char)(p01 & 0xff);
        ld[(quad * 4 + 1) * 16] = (unsigned char)((p01 >> 8) & 0xff);
        ld[(quad * 4 + 2) * 16] = (unsigned char)(p23 & 0xff);
        ld[(quad * 4 + 3) * 16] = (unsigned char)((p23 >> 8) & 0xff);
      }
    }
    __syncthreads();
    unsigned char* C8 = (unsigned char*)C;
    int mt2_0 = m0 >> 4, kp2_0 = n0 >> 6;
    #pragma unroll
    for (int p = 0; p < 4; ++p) {
      int ci = p * 256 + tid;
      int sb = ci >> 6, off = (ci & 63) * 16;
      int mt2 = mt2_0 + (sb >> 1), kp2 = kp2_0 + (sb & 1);
      *(int4*)(C8 + ((size_t)(mt2 * 64 + kp2)) * 1024 + off) =
          *(const int4*)(sC + sb * 1024 + off);
    }
  } else {
    float* O = (float*)C;
    #pragma unroll
    for (int i = 0; i < 4; ++i)
      #pragma unroll
      for (int j = 0; j < 4; ++j) {
        int col = n0 + wc * 64 + j * 16 + l15;
        #pragma unroll
        for (int v = 0; v < 4; ++v) {
          int row = m0 + wr * 64 + i * 16 + quad * 4 + v;
          atomicAdd(&O[(size_t)row * 1024 + col], acc[i][j][v] * 0.0625f);
        }
      }
  }
}

extern "C" void kernel_launch(void* const* d_in, const int* in_sizes, int n_in,
                              void* d_out, int out_size, void* d_ws, size_t ws_size,
                              hipStream_t stream) {
  const float* x     = (const float*)d_in[0];
  const float* log_A = (const float*)d_in[1];
  const float* w_dt  = (const float*)d_in[2];
  const float* b_dt  = (const float*)d_in[3];
  const float* g_ssm = (const float*)d_in[4];
  const float* b_ssm = (const float*)d_in[5];
  const float* g_ffn = (const float*)d_in[6];
  const float* b_ffn = (const float*)d_in[7];
  const float* W1    = (const float*)d_in[8];
  const float* bb1   = (const float*)d_in[9];
  const float* W2    = (const float*)d_in[10];
  const float* bb2   = (const float*)d_in[11];
  float* out = (float*)d_out;

  const size_t MB = 1u << 20;
  char* ws = (char*)d_ws;
  unsigned short* xn   = (unsigned short*)(ws);              // 0-4 bf16
  unsigned char* W1t   = (unsigned char*)(ws + 4 * MB);      // 4-8 fp8 pair-packed
  float* loga          = (float*)(ws + 8 * MB);              // 256 KB
  float4* Ebuf         = (float4*)(ws + 8 * MB + 262144);    // 64 KB
  float* Pbuf          = (float*)(ws + 8 * MB + 393216);     // 2 KB
  unsigned char* fn    = (unsigned char*)(ws + 9 * MB);      // 9-11 fp8 pair-packed
  unsigned char* W2t   = (unsigned char*)(ws + 11 * MB);     // 11-15 fp8 pair-packed
  unsigned char* hbf   = (unsigned char*)(ws + 15 * MB);     // 15-23 fp8 pair-packed

  k_pre<<<4096, 256, 0, stream>>>(x, g_ssm, b_ssm, w_dt, b_dt, log_A, xn, loga,
                                  W1, W1t, W2, W2t);
  k_scan_pass<0><<<512, 256, 0, stream>>>(xn, x, loga, Ebuf, Pbuf, bb2, out);
  k_scan_pass<1><<<512, 256, 0, stream>>>(xn, x, loga, Ebuf, Pbuf, bb2, out);
  k_ln2<<<2048, 256, 0, stream>>>(out, bb2, g_ffn, b_ffn, fn);
  // GEMM1: K=1024 (NKGP=16), 512 blocks
  k_gemm_lds<0, 16><<<512, 256, 0, stream>>>(fn, W1t, bb1, (void*)hbf);
  // GEMM2: K=4096 (NKGP=64), split-K=4, 512 blocks, atomic accumulate
  k_gemm_lds<1, 64><<<512, 256, 0, stream>>>(hbf, W2t, nullptr, (void*)out);
}